// Round 2
// baseline (1074.951 us; speedup 1.0000x reference)
//
#include <hip/hip_runtime.h>
#include <hip/hip_bf16.h>
#include <cstdint>
#include <cstddef>

#define N_NODES 50000
#define N_EDGES 800000

// ============================ CSR build ============================

__global__ void hist_kernel(const int* __restrict__ dst, int* __restrict__ deg, int E) {
    int e = blockIdx.x * 256 + threadIdx.x;
    if (e < E) atomicAdd(&deg[dst[e]], 1);
}

// single-block exclusive scan, 1024 elements per iteration (4/thread, wave shuffles)
__global__ void scan_kernel(const int* __restrict__ deg, int* __restrict__ row_ptr,
                            int* __restrict__ cursor, int n) {
    __shared__ int wsum[4];
    __shared__ int s_carry;
    int t = threadIdx.x, lane = t & 63, w = t >> 6;
    if (t == 0) s_carry = 0;
    __syncthreads();
    for (int base = 0; base < n; base += 1024) {
        int idx = base + t * 4;
        int v0 = 0, v1 = 0, v2 = 0, v3 = 0;
        if (idx + 3 < n) {
            int4 d = *(const int4*)(deg + idx);
            v0 = d.x; v1 = d.y; v2 = d.z; v3 = d.w;
        } else {
            if (idx     < n) v0 = deg[idx];
            if (idx + 1 < n) v1 = deg[idx + 1];
            if (idx + 2 < n) v2 = deg[idx + 2];
            if (idx + 3 < n) v3 = deg[idx + 3];
        }
        int tsum = v0 + v1 + v2 + v3;
        int sc = tsum;
        #pragma unroll
        for (int off = 1; off < 64; off <<= 1) {
            int u = __shfl_up(sc, off, 64);
            if (lane >= off) sc += u;
        }
        if (lane == 63) wsum[w] = sc;
        __syncthreads();
        int woff = 0;
        for (int i = 0; i < w; i++) woff += wsum[i];
        int excl = s_carry + woff + sc - tsum;
        if (idx < n)     { row_ptr[idx]     = excl; cursor[idx]     = excl; } excl += v0;
        if (idx + 1 < n) { row_ptr[idx + 1] = excl; cursor[idx + 1] = excl; } excl += v1;
        if (idx + 2 < n) { row_ptr[idx + 2] = excl; cursor[idx + 2] = excl; } excl += v2;
        if (idx + 3 < n) { row_ptr[idx + 3] = excl; cursor[idx + 3] = excl; }
        __syncthreads();
        if (t == 255) s_carry += wsum[0] + wsum[1] + wsum[2] + wsum[3];
        __syncthreads();
    }
    if (t == 0) row_ptr[n] = s_carry;
}

// pack src (16 bits, N<65536) | edge_type<<16
__global__ void fill_kernel(const int* __restrict__ src, const int* __restrict__ dst,
                            const int* __restrict__ et, int* __restrict__ cursor,
                            int* __restrict__ sorted, int E) {
    int e = blockIdx.x * 256 + threadIdx.x;
    if (e < E) {
        int pos = atomicAdd(&cursor[dst[e]], 1);
        sorted[pos] = src[e] | (et[e] << 16);
    }
}

// ============================ generic tiled GEMM ============================
// C[n, o] = sum_k A[n*K+k] * B(k,o) + bias[o], 128 output cols fixed.
// BT=1: B(k,o) = B[o*Kdim + k]   (linear: lin_w [128,64] row-major)
// BT=0: B(k,o) = B[k*128 + o]    (rgat: W reshaped [Kdim,128] row-major)
// tile: 64 nodes x 128 cols, BK=32. 256 threads, 4x8 acc each.

template<int BT>
__global__ __launch_bounds__(256) void gemm_k(const float* __restrict__ A,
                                              const float* __restrict__ B,
                                              const float* __restrict__ bias,
                                              float* __restrict__ C,
                                              int N, int Kdim, int relu) {
    __shared__ float As[32][64];    // [k][node]
    __shared__ float Bs[32][128];   // [k][col]
    int t = threadIdx.x;
    int n0 = blockIdx.x * 64;
    int rg = t >> 4;                // 0..15 -> 4 nodes each
    int cg = t & 15;                // 0..15 -> 8 cols each
    int an = t >> 2;                // A staging node (0..63)
    int ak = (t & 3) * 8;           // A staging k-offset (8 floats)
    float acc[4][8] = {};

    for (int k0 = 0; k0 < Kdim; k0 += 32) {
        // ---- stage A
        int gn = n0 + an;
        if (gn < N) {
            const float* ap = A + (size_t)gn * Kdim + k0 + ak;
            float4 v0 = *(const float4*)ap;
            float4 v1 = *(const float4*)(ap + 4);
            As[ak + 0][an] = v0.x; As[ak + 1][an] = v0.y;
            As[ak + 2][an] = v0.z; As[ak + 3][an] = v0.w;
            As[ak + 4][an] = v1.x; As[ak + 5][an] = v1.y;
            As[ak + 6][an] = v1.z; As[ak + 7][an] = v1.w;
        } else {
            #pragma unroll
            for (int c = 0; c < 8; c++) As[ak + c][an] = 0.f;
        }
        // ---- stage B
        if (BT) {
            int o = t >> 1, kh = (t & 1) * 16;
            const float* bp = B + (size_t)o * Kdim + k0 + kh;
            #pragma unroll
            for (int j = 0; j < 4; j++) {
                float4 v = ((const float4*)bp)[j];
                Bs[kh + j * 4 + 0][o] = v.x;
                Bs[kh + j * 4 + 1][o] = v.y;
                Bs[kh + j * 4 + 2][o] = v.z;
                Bs[kh + j * 4 + 3][o] = v.w;
            }
        } else {
            const float* bp = B + (size_t)k0 * 128 + t * 16;
            float* sp = &Bs[0][0] + t * 16;
            #pragma unroll
            for (int j = 0; j < 16; j += 4)
                *(float4*)(sp + j) = *(const float4*)(bp + j);
        }
        __syncthreads();
        // ---- inner product
        #pragma unroll
        for (int k = 0; k < 32; k++) {
            float a[4], b[8];
            *(float4*)&a[0] = *(const float4*)&As[k][rg * 4];
            *(float4*)&b[0] = *(const float4*)&Bs[k][cg * 8];
            *(float4*)&b[4] = *(const float4*)&Bs[k][cg * 8 + 4];
            #pragma unroll
            for (int i = 0; i < 4; i++)
                #pragma unroll
                for (int j = 0; j < 8; j++)
                    acc[i][j] = fmaf(a[i], b[j], acc[i][j]);
        }
        __syncthreads();
    }
    // ---- epilogue: bias (+relu), store
    #pragma unroll
    for (int i = 0; i < 4; i++) {
        int gn = n0 + rg * 4 + i;
        if (gn < N) {
            float v[8];
            #pragma unroll
            for (int j = 0; j < 8; j++) {
                float x = acc[i][j] + bias[cg * 8 + j];
                v[j] = relu ? fmaxf(x, 0.f) : x;
            }
            float* cp = C + (size_t)gn * 128 + cg * 8;
            *(float4*)cp       = *(float4*)&v[0];
            *(float4*)(cp + 4) = *(float4*)&v[4];
        }
    }
}

// ============================ wq = W@q, wk = W@k ============================

__global__ void wqk_kernel(const float* __restrict__ W, const float* __restrict__ q,
                           const float* __restrict__ k, float* __restrict__ wq,
                           float* __restrict__ wk) {
    int g = blockIdx.x * 256 + threadIdx.x;      // 0..2047
    int which = g >> 10;
    int r = (g >> 7) & 7;
    int i = g & 127;
    const float* vec = which ? k : q;
    const float* wrow = W + ((size_t)r * 128 + i) * 128;
    float acc = 0.f;
    #pragma unroll 4
    for (int o = 0; o < 128; o++) acc = fmaf(wrow[o], vec[o], acc);
    (which ? wk : wq)[r * 128 + i] = acc;
}

// ============================ Q[n,r], K[n,r] tables ============================

__global__ __launch_bounds__(256) void qk_table_kernel(const float* __restrict__ x,
                                                       const float* __restrict__ wq,
                                                       const float* __restrict__ wk,
                                                       float* __restrict__ Q,
                                                       float* __restrict__ K, int N) {
    int w = threadIdx.x >> 6, lane = threadIdx.x & 63;
    int n = blockIdx.x * 4 + w;
    if (n >= N) return;
    float x0 = x[(size_t)n * 128 + lane];
    float x1 = x[(size_t)n * 128 + 64 + lane];
    #pragma unroll
    for (int r = 0; r < 8; r++) {
        float pq = x0 * wq[r * 128 + lane] + x1 * wq[r * 128 + 64 + lane];
        float pk = x0 * wk[r * 128 + lane] + x1 * wk[r * 128 + 64 + lane];
        #pragma unroll
        for (int off = 32; off; off >>= 1) {
            pq += __shfl_xor(pq, off, 64);
            pk += __shfl_xor(pk, off, 64);
        }
        if (lane == 0) { Q[(size_t)n * 8 + r] = pq; K[(size_t)n * 8 + r] = pk; }
    }
}

// ============================ per-dst softmax + per-relation aggregate ============================
// s[n, et*128 + i] = sum_{e into n with type et} a_e * h[src_e, i]

__global__ __launch_bounds__(128) void agg_s_kernel(const float* __restrict__ h,
                                                    const float* __restrict__ Q,
                                                    const float* __restrict__ Kt,
                                                    const int* __restrict__ row_ptr,
                                                    const int* __restrict__ sorted,
                                                    float* __restrict__ alpha_g,
                                                    float* __restrict__ s, int N) {
    int n = blockIdx.x;
    int t = threadIdx.x;
    int beg = row_ptr[n], end = row_ptr[n + 1];
    int deg = end - beg;
    __shared__ float red[128];
    float acc[8] = {0.f, 0.f, 0.f, 0.f, 0.f, 0.f, 0.f, 0.f};

    if (deg > 0) {
        // pass 1: alpha + max
        float lmax = -INFINITY;
        for (int j = t; j < deg; j += 128) {
            int pk = sorted[beg + j];
            int src = pk & 0xFFFF;
            int et = pk >> 16;
            float a = Q[(size_t)n * 8 + et] + Kt[(size_t)src * 8 + et];
            a = (a > 0.f) ? a : 0.2f * a;                 // leaky_relu 0.2
            alpha_g[beg + j] = a;
            lmax = fmaxf(lmax, a);
        }
        red[t] = lmax;
        __syncthreads();
        #pragma unroll
        for (int off = 64; off; off >>= 1) {
            if (t < off) red[t] = fmaxf(red[t], red[t + off]);
            __syncthreads();
        }
        float m = red[0];
        __syncthreads();
        // pass 2: denom
        float lsum = 0.f;
        for (int j = t; j < deg; j += 128) lsum += __expf(alpha_g[beg + j] - m);
        red[t] = lsum;
        __syncthreads();
        #pragma unroll
        for (int off = 64; off; off >>= 1) {
            if (t < off) red[t] += red[t + off];
            __syncthreads();
        }
        float inv = 1.f / (red[0] + 1e-16f);
        // pass 3: weighted accumulate of h rows into per-relation acc
        for (int j = 0; j < deg; j++) {
            int pk = sorted[beg + j];
            int src = pk & 0xFFFF;
            int et = pk >> 16;                            // uniform across block
            float w = __expf(alpha_g[beg + j] - m) * inv;
            float x = h[(size_t)src * 128 + t];
            #pragma unroll
            for (int r = 0; r < 8; r++)
                if (et == r) acc[r] = fmaf(w, x, acc[r]);
        }
    }
    float* sp = s + (size_t)n * 1024;
    #pragma unroll
    for (int r = 0; r < 8; r++) sp[r * 128 + t] = acc[r];
}

// ============================ launch ============================

extern "C" void kernel_launch(void* const* d_in, const int* in_sizes, int n_in,
                              void* d_out, int out_size, void* d_ws, size_t ws_size,
                              hipStream_t stream) {
    const float* z     = (const float*)d_in[0];
    const float* lin_w = (const float*)d_in[1];
    const float* lin_b = (const float*)d_in[2];
    const float* w1    = (const float*)d_in[3];
    const float* q1    = (const float*)d_in[4];
    const float* k1    = (const float*)d_in[5];
    const float* b1    = (const float*)d_in[6];
    const float* w2    = (const float*)d_in[7];
    const float* q2    = (const float*)d_in[8];
    const float* k2    = (const float*)d_in[9];
    const float* b2    = (const float*)d_in[10];
    const int*   ei    = (const int*)d_in[11];
    const int*   et    = (const int*)d_in[12];
    float* out = (float*)d_out;

    char* ws = (char*)d_ws;
    size_t off = 0;
    auto alloc = [&](size_t bytes) -> void* {
        void* p = ws + off;
        off += (bytes + 255) & ~(size_t)255;
        return p;
    };
    float* s     = (float*)alloc((size_t)N_NODES * 1024 * 4);   // 204.8 MB
    float* h     = (float*)alloc((size_t)N_NODES * 128 * 4);    // 25.6 MB
    float* Q     = (float*)alloc((size_t)N_NODES * 8 * 4);
    float* K     = (float*)alloc((size_t)N_NODES * 8 * 4);
    float* alpha = (float*)alloc((size_t)N_EDGES * 4);
    int* sorted  = (int*)alloc((size_t)N_EDGES * 4);
    int* deg     = (int*)alloc((size_t)N_NODES * 4);
    int* rowp    = (int*)alloc((size_t)(N_NODES + 1) * 4);
    int* cursor  = (int*)alloc((size_t)N_NODES * 4);
    float* wq    = (float*)alloc(8 * 128 * 4);
    float* wk    = (float*)alloc(8 * 128 * 4);

    const int* src = ei;
    const int* dst = ei + N_EDGES;

    // CSR build (rebuilt every call: ws is re-poisoned)
    hipMemsetAsync(deg, 0, (size_t)N_NODES * 4, stream);
    hist_kernel<<<(N_EDGES + 255) / 256, 256, 0, stream>>>(dst, deg, N_EDGES);
    scan_kernel<<<1, 256, 0, stream>>>(deg, rowp, cursor, N_NODES);
    fill_kernel<<<(N_EDGES + 255) / 256, 256, 0, stream>>>(src, dst, et, cursor, sorted, N_EDGES);

    int ggrid = (N_NODES + 63) / 64;   // 782

    // h = z @ lin_w.T + lin_b   (BT=1, K=64, no relu)
    gemm_k<1><<<ggrid, 256, 0, stream>>>(z, lin_w, lin_b, h, N_NODES, 64, 0);

    // ---- layer 1: h -> h  (relu on output)
    wqk_kernel<<<8, 256, 0, stream>>>(w1, q1, k1, wq, wk);
    qk_table_kernel<<<(N_NODES + 3) / 4, 256, 0, stream>>>(h, wq, wk, Q, K, N_NODES);
    agg_s_kernel<<<N_NODES, 128, 0, stream>>>(h, Q, K, rowp, sorted, alpha, s, N_NODES);
    gemm_k<0><<<ggrid, 256, 0, stream>>>(s, w1, b1, h, N_NODES, 1024, 1);

    // ---- layer 2: h -> out (no relu)
    wqk_kernel<<<8, 256, 0, stream>>>(w2, q2, k2, wq, wk);
    qk_table_kernel<<<(N_NODES + 3) / 4, 256, 0, stream>>>(h, wq, wk, Q, K, N_NODES);
    agg_s_kernel<<<N_NODES, 128, 0, stream>>>(h, Q, K, rowp, sorted, alpha, s, N_NODES);
    gemm_k<0><<<ggrid, 256, 0, stream>>>(s, w2, b2, out, N_NODES, 1024, 0);
}

// Round 3
// 762.630 us; speedup vs baseline: 1.4095x; 1.4095x over previous
//
#include <hip/hip_runtime.h>
#include <hip/hip_bf16.h>
#include <cstdint>
#include <cstddef>

#define N_NODES 50000
#define N_EDGES 800000
#define NPAD    50048            // 391 * 128

using frag_t = __attribute__((ext_vector_type(8))) short;   // 8 bf16 (4 VGPRs)
using f32x4  = __attribute__((ext_vector_type(4))) float;   // 4 fp32 acc

__device__ __forceinline__ short f2bf(float x) {
    __hip_bfloat16 h = __float2bfloat16(x);
    return *reinterpret_cast<short*>(&h);
}

// ============================ CSR build ============================

__global__ void hist_kernel(const int* __restrict__ dst, int* __restrict__ deg, int E) {
    int e = blockIdx.x * 256 + threadIdx.x;
    if (e < E) atomicAdd(&deg[dst[e]], 1);
}

__global__ void scan_kernel(const int* __restrict__ deg, int* __restrict__ row_ptr,
                            int* __restrict__ cursor, int n) {
    __shared__ int wsum[4];
    __shared__ int s_carry;
    int t = threadIdx.x, lane = t & 63, w = t >> 6;
    if (t == 0) s_carry = 0;
    __syncthreads();
    for (int base = 0; base < n; base += 1024) {
        int idx = base + t * 4;
        int v0 = 0, v1 = 0, v2 = 0, v3 = 0;
        if (idx + 3 < n) {
            int4 d = *(const int4*)(deg + idx);
            v0 = d.x; v1 = d.y; v2 = d.z; v3 = d.w;
        } else {
            if (idx     < n) v0 = deg[idx];
            if (idx + 1 < n) v1 = deg[idx + 1];
            if (idx + 2 < n) v2 = deg[idx + 2];
            if (idx + 3 < n) v3 = deg[idx + 3];
        }
        int tsum = v0 + v1 + v2 + v3;
        int sc = tsum;
        #pragma unroll
        for (int off = 1; off < 64; off <<= 1) {
            int u = __shfl_up(sc, off, 64);
            if (lane >= off) sc += u;
        }
        if (lane == 63) wsum[w] = sc;
        __syncthreads();
        int woff = 0;
        for (int i = 0; i < w; i++) woff += wsum[i];
        int excl = s_carry + woff + sc - tsum;
        if (idx < n)     { row_ptr[idx]     = excl; cursor[idx]     = excl; } excl += v0;
        if (idx + 1 < n) { row_ptr[idx + 1] = excl; cursor[idx + 1] = excl; } excl += v1;
        if (idx + 2 < n) { row_ptr[idx + 2] = excl; cursor[idx + 2] = excl; } excl += v2;
        if (idx + 3 < n) { row_ptr[idx + 3] = excl; cursor[idx + 3] = excl; }
        __syncthreads();
        if (t == 255) s_carry += wsum[0] + wsum[1] + wsum[2] + wsum[3];
        __syncthreads();
    }
    if (t == 0) row_ptr[n] = s_carry;
}

__global__ void fill_kernel(const int* __restrict__ src, const int* __restrict__ dst,
                            const int* __restrict__ et, int* __restrict__ cursor,
                            int* __restrict__ sorted, int E) {
    int e = blockIdx.x * 256 + threadIdx.x;
    if (e < E) {
        int pos = atomicAdd(&cursor[dst[e]], 1);
        sorted[pos] = src[e] | (et[e] << 16);
    }
}

// ============================ fp32 tiled GEMM (linear layer only, K=64) ============================

__global__ __launch_bounds__(256) void gemm_lin(const float* __restrict__ A,
                                                const float* __restrict__ B,
                                                const float* __restrict__ bias,
                                                float* __restrict__ C, int N) {
    const int Kdim = 64;
    __shared__ float As[32][64];
    __shared__ float Bs[32][128];
    int t = threadIdx.x;
    int n0 = blockIdx.x * 64;
    int rg = t >> 4, cg = t & 15;
    int an = t >> 2, ak = (t & 3) * 8;
    float acc[4][8] = {};

    for (int k0 = 0; k0 < Kdim; k0 += 32) {
        int gn = n0 + an;
        if (gn < N) {
            const float* ap = A + (size_t)gn * Kdim + k0 + ak;
            float4 v0 = *(const float4*)ap;
            float4 v1 = *(const float4*)(ap + 4);
            As[ak + 0][an] = v0.x; As[ak + 1][an] = v0.y;
            As[ak + 2][an] = v0.z; As[ak + 3][an] = v0.w;
            As[ak + 4][an] = v1.x; As[ak + 5][an] = v1.y;
            As[ak + 6][an] = v1.z; As[ak + 7][an] = v1.w;
        } else {
            #pragma unroll
            for (int c = 0; c < 8; c++) As[ak + c][an] = 0.f;
        }
        {   // B is lin_w [128 out][64 in] row-major -> need B(k,o)
            int o = t >> 1, kh = (t & 1) * 16;
            const float* bp = B + (size_t)o * Kdim + k0 + kh;
            #pragma unroll
            for (int j = 0; j < 4; j++) {
                float4 v = ((const float4*)bp)[j];
                Bs[kh + j * 4 + 0][o] = v.x;
                Bs[kh + j * 4 + 1][o] = v.y;
                Bs[kh + j * 4 + 2][o] = v.z;
                Bs[kh + j * 4 + 3][o] = v.w;
            }
        }
        __syncthreads();
        #pragma unroll
        for (int k = 0; k < 32; k++) {
            float a[4], b[8];
            *(float4*)&a[0] = *(const float4*)&As[k][rg * 4];
            *(float4*)&b[0] = *(const float4*)&Bs[k][cg * 8];
            *(float4*)&b[4] = *(const float4*)&Bs[k][cg * 8 + 4];
            #pragma unroll
            for (int i = 0; i < 4; i++)
                #pragma unroll
                for (int j = 0; j < 8; j++)
                    acc[i][j] = fmaf(a[i], b[j], acc[i][j]);
        }
        __syncthreads();
    }
    #pragma unroll
    for (int i = 0; i < 4; i++) {
        int gn = n0 + rg * 4 + i;
        if (gn < N) {
            float v[8];
            #pragma unroll
            for (int j = 0; j < 8; j++) v[j] = acc[i][j] + bias[cg * 8 + j];
            float* cp = C + (size_t)gn * 128 + cg * 8;
            *(float4*)cp       = *(float4*)&v[0];
            *(float4*)(cp + 4) = *(float4*)&v[4];
        }
    }
}

// ============================ W fp32 -> bf16 B-fragment-blocked ============================
// Bf[(k>>3)*128*8 + o*8 + (k&7)] = bf16(W[k*128 + o]),  k = r*128+i, 1024x128

__global__ void wconv_kernel(const float* __restrict__ W, short* __restrict__ Bf) {
    int idx = blockIdx.x * 256 + threadIdx.x;    // 131072
    int k = idx >> 7, o = idx & 127;
    float v = W[(size_t)k * 128 + o];
    Bf[(((size_t)(k >> 3) * 128) + o) * 8 + (k & 7)] = f2bf(v);
}

// ============================ wq = W@q, wk = W@k ============================

__global__ void wqk_kernel(const float* __restrict__ W, const float* __restrict__ q,
                           const float* __restrict__ k, float* __restrict__ wq,
                           float* __restrict__ wk) {
    int g = blockIdx.x * 256 + threadIdx.x;
    int which = g >> 10;
    int r = (g >> 7) & 7;
    int i = g & 127;
    const float* vec = which ? k : q;
    const float* wrow = W + ((size_t)r * 128 + i) * 128;
    float acc = 0.f;
    #pragma unroll 4
    for (int o = 0; o < 128; o++) acc = fmaf(wrow[o], vec[o], acc);
    (which ? wk : wq)[r * 128 + i] = acc;
}

// ============================ Q[n,r], K[n,r] tables ============================

__global__ __launch_bounds__(256) void qk_table_kernel(const float* __restrict__ x,
                                                       const float* __restrict__ wq,
                                                       const float* __restrict__ wk,
                                                       float* __restrict__ Q,
                                                       float* __restrict__ K, int N) {
    int w = threadIdx.x >> 6, lane = threadIdx.x & 63;
    int n = blockIdx.x * 4 + w;
    if (n >= N) return;
    float x0 = x[(size_t)n * 128 + lane];
    float x1 = x[(size_t)n * 128 + 64 + lane];
    #pragma unroll
    for (int r = 0; r < 8; r++) {
        float pq = x0 * wq[r * 128 + lane] + x1 * wq[r * 128 + 64 + lane];
        float pk = x0 * wk[r * 128 + lane] + x1 * wk[r * 128 + 64 + lane];
        #pragma unroll
        for (int off = 32; off; off >>= 1) {
            pq += __shfl_xor(pq, off, 64);
            pk += __shfl_xor(pk, off, 64);
        }
        if (lane == 0) { Q[(size_t)n * 8 + r] = pq; K[(size_t)n * 8 + r] = pk; }
    }
}

// ============================ per-dst softmax + per-relation aggregate ============================
// Writes Af[kb][node][8] bf16 (MFMA A-fragment blocked), kb = (r*128+c)>>3

__global__ __launch_bounds__(128) void agg_s_kernel(const float* __restrict__ h,
                                                    const float* __restrict__ Q,
                                                    const float* __restrict__ Kt,
                                                    const int* __restrict__ row_ptr,
                                                    const int* __restrict__ sorted,
                                                    float* __restrict__ alpha_g,
                                                    short* __restrict__ Af, int N) {
    int n = blockIdx.x;
    int t = threadIdx.x;
    int beg = 0, deg = 0;
    if (n < N) { beg = row_ptr[n]; deg = row_ptr[n + 1] - beg; }
    __shared__ float red[128];
    float acc[8] = {0.f, 0.f, 0.f, 0.f, 0.f, 0.f, 0.f, 0.f};

    if (deg > 0) {
        float lmax = -INFINITY;
        for (int j = t; j < deg; j += 128) {
            int pk = sorted[beg + j];
            int src = pk & 0xFFFF;
            int et = pk >> 16;
            float a = Q[(size_t)n * 8 + et] + Kt[(size_t)src * 8 + et];
            a = (a > 0.f) ? a : 0.2f * a;                 // leaky_relu 0.2
            alpha_g[beg + j] = a;
            lmax = fmaxf(lmax, a);
        }
        red[t] = lmax;
        __syncthreads();
        #pragma unroll
        for (int off = 64; off; off >>= 1) {
            if (t < off) red[t] = fmaxf(red[t], red[t + off]);
            __syncthreads();
        }
        float m = red[0];
        __syncthreads();
        float lsum = 0.f;
        for (int j = t; j < deg; j += 128) {
            float e = __expf(alpha_g[beg + j] - m);
            alpha_g[beg + j] = e;                          // store exp for pass 3
            lsum += e;
        }
        red[t] = lsum;
        __syncthreads();
        #pragma unroll
        for (int off = 64; off; off >>= 1) {
            if (t < off) red[t] += red[t + off];
            __syncthreads();
        }
        float inv = 1.f / (red[0] + 1e-16f);
        for (int j = 0; j < deg; j++) {
            int pk = sorted[beg + j];
            int src = pk & 0xFFFF;
            int et = pk >> 16;
            float w = alpha_g[beg + j] * inv;
            float x = h[(size_t)src * 128 + t];
            #pragma unroll
            for (int r = 0; r < 8; r++)
                if (et == r) acc[r] = fmaf(w, x, acc[r]);
        }
    }
    // store bf16 fragment-blocked: k = r*128 + t, kb = r*16 + (t>>3), j = t&7
    #pragma unroll
    for (int r = 0; r < 8; r++)
        Af[((size_t)(r * 16 + (t >> 3)) * NPAD + n) * 8 + (t & 7)] = f2bf(acc[r]);
}

// ============================ MFMA GEMM: C[n,o] = Af[n,:]@Bf + bias ============================
// K=1024. Block: 128 rows x 128 cols, 256 threads (4 waves x 2 row-tiles x 8 col-tiles).

__global__ __launch_bounds__(256) void gemm_mfma(const short* __restrict__ Af,
                                                 const short* __restrict__ Bf,
                                                 const float* __restrict__ bias,
                                                 float* __restrict__ C,
                                                 int N, int relu) {
    __shared__ short Bs[4096];                    // 4 kb x 128 col x 8 = 8 KB
    int t = threadIdx.x;
    int w = t >> 6, lane = t & 63;
    int lhi = lane >> 4, llo = lane & 15;
    int n0 = blockIdx.x * 128;
    int row0 = n0 + w * 32 + llo;                 // A-frag row, row-tile 0
    f32x4 acc[16] = {};                           // [rt*8 + ct]

    for (int kb0 = 0; kb0 < 128; kb0 += 4) {
        // stage B chunk (8 KB, contiguous): 256 threads x 32 B
        {
            const short* sp = Bf + (size_t)kb0 * 1024 + t * 16;
            short* dp = Bs + t * 16;
            *(int4*)dp       = *(const int4*)sp;
            *(int4*)(dp + 8) = *(const int4*)(sp + 8);
        }
        // A fragments direct from global (256 B segments per lhi group)
        frag_t a0 = *(const frag_t*)(Af + ((size_t)(kb0 + lhi) * NPAD + row0) * 8);
        frag_t a1 = *(const frag_t*)(Af + ((size_t)(kb0 + lhi) * NPAD + row0 + 16) * 8);
        __syncthreads();
        #pragma unroll
        for (int ct = 0; ct < 8; ct++) {
            frag_t b = *(const frag_t*)(Bs + ((size_t)lhi * 128 + ct * 16 + llo) * 8);
            acc[ct]     = __builtin_amdgcn_mfma_f32_16x16x32_bf16(a0, b, acc[ct], 0, 0, 0);
            acc[8 + ct] = __builtin_amdgcn_mfma_f32_16x16x32_bf16(a1, b, acc[8 + ct], 0, 0, 0);
        }
        __syncthreads();
    }
    // epilogue: C/D layout col = llo, row = lhi*4 + reg
    #pragma unroll
    for (int rt = 0; rt < 2; rt++) {
        #pragma unroll
        for (int ct = 0; ct < 8; ct++) {
            int col = ct * 16 + llo;
            float bv = bias[col];
            #pragma unroll
            for (int rg = 0; rg < 4; rg++) {
                int rown = n0 + w * 32 + rt * 16 + lhi * 4 + rg;
                if (rown < N) {
                    float v = acc[rt * 8 + ct][rg] + bv;
                    if (relu) v = fmaxf(v, 0.f);
                    C[(size_t)rown * 128 + col] = v;
                }
            }
        }
    }
}

// ============================ launch ============================

extern "C" void kernel_launch(void* const* d_in, const int* in_sizes, int n_in,
                              void* d_out, int out_size, void* d_ws, size_t ws_size,
                              hipStream_t stream) {
    const float* z     = (const float*)d_in[0];
    const float* lin_w = (const float*)d_in[1];
    const float* lin_b = (const float*)d_in[2];
    const float* w1    = (const float*)d_in[3];
    const float* q1    = (const float*)d_in[4];
    const float* k1    = (const float*)d_in[5];
    const float* b1    = (const float*)d_in[6];
    const float* w2    = (const float*)d_in[7];
    const float* q2    = (const float*)d_in[8];
    const float* k2    = (const float*)d_in[9];
    const float* b2    = (const float*)d_in[10];
    const int*   ei    = (const int*)d_in[11];
    const int*   et    = (const int*)d_in[12];
    float* out = (float*)d_out;

    char* ws = (char*)d_ws;
    size_t off = 0;
    auto alloc = [&](size_t bytes) -> void* {
        void* p = ws + off;
        off += (bytes + 255) & ~(size_t)255;
        return p;
    };
    short* Af    = (short*)alloc((size_t)128 * NPAD * 8 * 2);   // 102.5 MB bf16 blocked
    float* h     = (float*)alloc((size_t)N_NODES * 128 * 4);    // 25.6 MB
    float* Q     = (float*)alloc((size_t)N_NODES * 8 * 4);
    float* K     = (float*)alloc((size_t)N_NODES * 8 * 4);
    float* alpha = (float*)alloc((size_t)N_EDGES * 4);
    int* sorted  = (int*)alloc((size_t)N_EDGES * 4);
    int* deg     = (int*)alloc((size_t)N_NODES * 4);
    int* rowp    = (int*)alloc((size_t)(N_NODES + 1) * 4);
    int* cursor  = (int*)alloc((size_t)N_NODES * 4);
    float* wq    = (float*)alloc(8 * 128 * 4);
    float* wk    = (float*)alloc(8 * 128 * 4);
    short* Bf    = (short*)alloc((size_t)1024 * 128 * 2);       // 256 KB bf16 blocked

    const int* src = ei;
    const int* dst = ei + N_EDGES;

    // CSR build
    hipMemsetAsync(deg, 0, (size_t)N_NODES * 4, stream);
    hist_kernel<<<(N_EDGES + 255) / 256, 256, 0, stream>>>(dst, deg, N_EDGES);
    scan_kernel<<<1, 256, 0, stream>>>(deg, rowp, cursor, N_NODES);
    fill_kernel<<<(N_EDGES + 255) / 256, 256, 0, stream>>>(src, dst, et, cursor, sorted, N_EDGES);

    // h = z @ lin_w.T + lin_b
    gemm_lin<<<(N_NODES + 63) / 64, 256, 0, stream>>>(z, lin_w, lin_b, h, N_NODES);

    int mgrid = NPAD / 128;   // 391

    // ---- layer 1: h -> h (relu)
    wconv_kernel<<<512, 256, 0, stream>>>(w1, Bf);
    wqk_kernel<<<8, 256, 0, stream>>>(w1, q1, k1, wq, wk);
    qk_table_kernel<<<(N_NODES + 3) / 4, 256, 0, stream>>>(h, wq, wk, Q, K, N_NODES);
    agg_s_kernel<<<NPAD, 128, 0, stream>>>(h, Q, K, rowp, sorted, alpha, Af, N_NODES);
    gemm_mfma<<<mgrid, 256, 0, stream>>>(Af, Bf, b1, h, N_NODES, 1);

    // ---- layer 2: h -> out (no relu)
    wconv_kernel<<<512, 256, 0, stream>>>(w2, Bf);
    wqk_kernel<<<8, 256, 0, stream>>>(w2, q2, k2, wq, wk);
    qk_table_kernel<<<(N_NODES + 3) / 4, 256, 0, stream>>>(h, wq, wk, Q, K, N_NODES);
    agg_s_kernel<<<NPAD, 128, 0, stream>>>(h, Q, K, rowp, sorted, alpha, Af, N_NODES);
    gemm_mfma<<<mgrid, 256, 0, stream>>>(Af, Bf, b2, out, N_NODES, 0);
}

// Round 4
// 620.187 us; speedup vs baseline: 1.7333x; 1.2297x over previous
//
#include <hip/hip_runtime.h>
#include <hip/hip_bf16.h>
#include <cstdint>
#include <cstddef>

#define N_NODES 50000
#define N_EDGES 800000
#define NSEG    (N_NODES * 8)            // 400000 (dst,et) buckets

using frag_t = __attribute__((ext_vector_type(8))) short;   // 8 bf16 (4 VGPRs)
using f32x4  = __attribute__((ext_vector_type(4))) float;   // 4 fp32 acc

__device__ __forceinline__ short f2bf(float x) {
    __hip_bfloat16 h = __float2bfloat16(x);
    return *reinterpret_cast<short*>(&h);
}
__device__ __forceinline__ float bf2f(unsigned short u) {
    union { unsigned int i; float f; } v;
    v.i = ((unsigned int)u) << 16;
    return v.f;
}

// ============================ CSR build over (dst*8 + et) ============================

__global__ void hist_kernel(const int* __restrict__ dst, const int* __restrict__ et,
                            int* __restrict__ deg8, int E) {
    int e = blockIdx.x * 256 + threadIdx.x;
    if (e < E) atomicAdd(&deg8[dst[e] * 8 + et[e]], 1);
}

// hierarchical scan: (1) per-1024-chunk partial sums
__global__ __launch_bounds__(256) void scan_part(const int* __restrict__ deg8,
                                                 int* __restrict__ part, int M) {
    __shared__ int red[256];
    int t = threadIdx.x;
    int idx = blockIdx.x * 1024 + t * 4;
    int s = 0;
    if (idx + 3 < M) {
        int4 d = *(const int4*)(deg8 + idx);
        s = d.x + d.y + d.z + d.w;
    } else {
        for (int c = 0; c < 4; c++) if (idx + c < M) s += deg8[idx + c];
    }
    red[t] = s;
    __syncthreads();
    #pragma unroll
    for (int off = 128; off; off >>= 1) {
        if (t < off) red[t] += red[t + off];
        __syncthreads();
    }
    if (t == 0) part[blockIdx.x] = red[0];
}

// (2) single-block exclusive scan of partials (nparts <= 512)
__global__ __launch_bounds__(512) void scan_mid(int* __restrict__ part, int nparts,
                                                int* __restrict__ rowp, int M) {
    __shared__ int buf[512];
    int t = threadIdx.x;
    int own = (t < nparts) ? part[t] : 0;
    buf[t] = own;
    __syncthreads();
    for (int off = 1; off < 512; off <<= 1) {
        int v = buf[t];
        int u = (t >= off) ? buf[t - off] : 0;
        __syncthreads();
        buf[t] = v + u;
        __syncthreads();
    }
    if (t < nparts) part[t] = buf[t] - own;    // exclusive
    if (t == 511) rowp[M] = buf[511];          // total
}

// (3) fixup: local scan + chunk offset -> rowp, cursor
__global__ __launch_bounds__(256) void scan_fix(const int* __restrict__ deg8,
                                                const int* __restrict__ part,
                                                int* __restrict__ rowp,
                                                int* __restrict__ cursor, int M) {
    __shared__ int wsum[4];
    int t = threadIdx.x, lane = t & 63, w = t >> 6;
    int idx = blockIdx.x * 1024 + t * 4;
    int v0 = 0, v1 = 0, v2 = 0, v3 = 0;
    if (idx + 3 < M) {
        int4 d = *(const int4*)(deg8 + idx);
        v0 = d.x; v1 = d.y; v2 = d.z; v3 = d.w;
    } else {
        if (idx     < M) v0 = deg8[idx];
        if (idx + 1 < M) v1 = deg8[idx + 1];
        if (idx + 2 < M) v2 = deg8[idx + 2];
        if (idx + 3 < M) v3 = deg8[idx + 3];
    }
    int tsum = v0 + v1 + v2 + v3;
    int sc = tsum;
    #pragma unroll
    for (int off = 1; off < 64; off <<= 1) {
        int u = __shfl_up(sc, off, 64);
        if (lane >= off) sc += u;
    }
    if (lane == 63) wsum[w] = sc;
    __syncthreads();
    int woff = 0;
    for (int i = 0; i < w; i++) woff += wsum[i];
    int excl = part[blockIdx.x] + woff + sc - tsum;
    if (idx     < M) { rowp[idx]     = excl; cursor[idx]     = excl; } excl += v0;
    if (idx + 1 < M) { rowp[idx + 1] = excl; cursor[idx + 1] = excl; } excl += v1;
    if (idx + 2 < M) { rowp[idx + 2] = excl; cursor[idx + 2] = excl; } excl += v2;
    if (idx + 3 < M) { rowp[idx + 3] = excl; cursor[idx + 3] = excl; }
}

// pack src (16 bits) | edge_type<<16
__global__ void fill_kernel(const int* __restrict__ src, const int* __restrict__ dst,
                            const int* __restrict__ et, int* __restrict__ cursor,
                            int* __restrict__ sorted, int E) {
    int e = blockIdx.x * 256 + threadIdx.x;
    if (e < E) {
        int pos = atomicAdd(&cursor[dst[e] * 8 + et[e]], 1);
        sorted[pos] = src[e] | (et[e] << 16);
    }
}

// ============================ fp32 tiled GEMM (linear layer, K=64) ============================

__global__ __launch_bounds__(256) void gemm_lin(const float* __restrict__ A,
                                                const float* __restrict__ B,
                                                const float* __restrict__ bias,
                                                float* __restrict__ C,
                                                unsigned short* __restrict__ hb, int N) {
    const int Kdim = 64;
    __shared__ float As[32][64];
    __shared__ float Bs[32][128];
    int t = threadIdx.x;
    int n0 = blockIdx.x * 64;
    int rg = t >> 4, cg = t & 15;
    int an = t >> 2, ak = (t & 3) * 8;
    float acc[4][8] = {};

    for (int k0 = 0; k0 < Kdim; k0 += 32) {
        int gn = n0 + an;
        if (gn < N) {
            const float* ap = A + (size_t)gn * Kdim + k0 + ak;
            float4 v0 = *(const float4*)ap;
            float4 v1 = *(const float4*)(ap + 4);
            As[ak + 0][an] = v0.x; As[ak + 1][an] = v0.y;
            As[ak + 2][an] = v0.z; As[ak + 3][an] = v0.w;
            As[ak + 4][an] = v1.x; As[ak + 5][an] = v1.y;
            As[ak + 6][an] = v1.z; As[ak + 7][an] = v1.w;
        } else {
            #pragma unroll
            for (int c = 0; c < 8; c++) As[ak + c][an] = 0.f;
        }
        {
            int o = t >> 1, kh = (t & 1) * 16;
            const float* bp = B + (size_t)o * Kdim + k0 + kh;
            #pragma unroll
            for (int j = 0; j < 4; j++) {
                float4 v = ((const float4*)bp)[j];
                Bs[kh + j * 4 + 0][o] = v.x;
                Bs[kh + j * 4 + 1][o] = v.y;
                Bs[kh + j * 4 + 2][o] = v.z;
                Bs[kh + j * 4 + 3][o] = v.w;
            }
        }
        __syncthreads();
        #pragma unroll
        for (int k = 0; k < 32; k++) {
            float a[4], b[8];
            *(float4*)&a[0] = *(const float4*)&As[k][rg * 4];
            *(float4*)&b[0] = *(const float4*)&Bs[k][cg * 8];
            *(float4*)&b[4] = *(const float4*)&Bs[k][cg * 8 + 4];
            #pragma unroll
            for (int i = 0; i < 4; i++)
                #pragma unroll
                for (int j = 0; j < 8; j++)
                    acc[i][j] = fmaf(a[i], b[j], acc[i][j]);
        }
        __syncthreads();
    }
    #pragma unroll
    for (int i = 0; i < 4; i++) {
        int gn = n0 + rg * 4 + i;
        if (gn < N) {
            float v[8];
            unsigned short us[8];
            #pragma unroll
            for (int j = 0; j < 8; j++) {
                v[j] = acc[i][j] + bias[cg * 8 + j];
                us[j] = (unsigned short)f2bf(v[j]);
            }
            float* cp = C + (size_t)gn * 128 + cg * 8;
            *(float4*)cp       = *(float4*)&v[0];
            *(float4*)(cp + 4) = *(float4*)&v[4];
            *(int4*)(hb + (size_t)gn * 128 + cg * 8) = *(int4*)&us[0];
        }
    }
}

// ============================ W fp32 -> bf16 B-fragment-blocked ============================
// Bf[(k>>3)*128*8 + o*8 + (k&7)] = bf16(W[k*128 + o])

__global__ void wconv_kernel(const float* __restrict__ W, short* __restrict__ Bf) {
    int idx = blockIdx.x * 256 + threadIdx.x;    // 131072
    int k = idx >> 7, o = idx & 127;
    float v = W[(size_t)k * 128 + o];
    Bf[(((size_t)(k >> 3) * 128) + o) * 8 + (k & 7)] = f2bf(v);
}

// ============================ wq = W@q, wk = W@k ============================

__global__ void wqk_kernel(const float* __restrict__ W, const float* __restrict__ q,
                           const float* __restrict__ k, float* __restrict__ wq,
                           float* __restrict__ wk) {
    int g = blockIdx.x * 256 + threadIdx.x;
    int which = g >> 10;
    int r = (g >> 7) & 7;
    int i = g & 127;
    const float* vec = which ? k : q;
    const float* wrow = W + ((size_t)r * 128 + i) * 128;
    float acc = 0.f;
    #pragma unroll 4
    for (int o = 0; o < 128; o++) acc = fmaf(wrow[o], vec[o], acc);
    (which ? wk : wq)[r * 128 + i] = acc;
}

// ============================ Q[n,r], K[n,r] tables (fp32 h) ============================

__global__ __launch_bounds__(256) void qk_table_kernel(const float* __restrict__ x,
                                                       const float* __restrict__ wq,
                                                       const float* __restrict__ wk,
                                                       float* __restrict__ Q,
                                                       float* __restrict__ K, int N) {
    int w = threadIdx.x >> 6, lane = threadIdx.x & 63;
    int n = blockIdx.x * 4 + w;
    if (n >= N) return;
    float x0 = x[(size_t)n * 128 + lane];
    float x1 = x[(size_t)n * 128 + 64 + lane];
    #pragma unroll
    for (int r = 0; r < 8; r++) {
        float pq = x0 * wq[r * 128 + lane] + x1 * wq[r * 128 + 64 + lane];
        float pk = x0 * wk[r * 128 + lane] + x1 * wk[r * 128 + 64 + lane];
        #pragma unroll
        for (int off = 32; off; off >>= 1) {
            pq += __shfl_xor(pq, off, 64);
            pk += __shfl_xor(pk, off, 64);
        }
        if (lane == 0) { Q[(size_t)n * 8 + r] = pq; K[(size_t)n * 8 + r] = pk; }
    }
}

// ============================ per-dst softmax + per-(dst,rel)-segment aggregate ============================
// s[n*1024 + r*128 + t] = bf16( sum_{e in seg(n,r)} a_e * hb[src_e, t] )

__global__ __launch_bounds__(128) void agg_s_kernel(const unsigned short* __restrict__ hb,
                                                    const float* __restrict__ Q,
                                                    const float* __restrict__ Kt,
                                                    const int* __restrict__ rowp8,
                                                    const int* __restrict__ sorted,
                                                    float* __restrict__ alpha_g,
                                                    short* __restrict__ s, int N) {
    int n = blockIdx.x;
    int t = threadIdx.x;
    __shared__ int segs[9];
    __shared__ float red[128];
    if (t < 9) segs[t] = rowp8[n * 8 + t];
    __syncthreads();
    int beg = segs[0], end = segs[8];
    int deg = end - beg;
    short* sp = s + (size_t)n * 1024;

    if (deg == 0) {
        int4 z = {0, 0, 0, 0};
        *(int4*)(sp + t * 8) = z;     // 128 x 16 B = full 2 KB row of zeros
        return;
    }

    // pass 1: logits + max
    float lmax = -INFINITY;
    for (int j = beg + t; j < end; j += 128) {
        int pk = sorted[j];
        int srcn = pk & 0xFFFF;
        int et = pk >> 16;
        float a = Q[(size_t)n * 8 + et] + Kt[(size_t)srcn * 8 + et];
        a = (a > 0.f) ? a : 0.2f * a;                  // leaky_relu 0.2
        alpha_g[j] = a;
        lmax = fmaxf(lmax, a);
    }
    red[t] = lmax;
    __syncthreads();
    #pragma unroll
    for (int off = 64; off; off >>= 1) {
        if (t < off) red[t] = fmaxf(red[t], red[t + off]);
        __syncthreads();
    }
    float m = red[0];
    __syncthreads();

    // pass 2: exp + denom (store exp)
    float lsum = 0.f;
    for (int j = beg + t; j < end; j += 128) {
        float e = __expf(alpha_g[j] - m);
        alpha_g[j] = e;
        lsum += e;
    }
    red[t] = lsum;
    __syncthreads();
    #pragma unroll
    for (int off = 64; off; off >>= 1) {
        if (t < off) red[t] += red[t + off];
        __syncthreads();
    }
    float inv = 1.f / (red[0] + 1e-16f);

    // pass 3: per-relation segment, unpredicated accumulate
    #pragma unroll
    for (int r = 0; r < 8; r++) {
        float a = 0.f;
        for (int j = segs[r]; j < segs[r + 1]; j++) {
            int srcn = sorted[j] & 0xFFFF;
            float x = bf2f(hb[(size_t)srcn * 128 + t]);
            a = fmaf(alpha_g[j] * inv, x, a);
        }
        sp[r * 128 + t] = f2bf(a);
    }
}

// ============================ MFMA GEMM: C[n,o] = s[n,:]@Bf + bias ============================
// K=1024. Block: 128 rows x 128 cols, 256 threads (4 waves x 2 row-tiles x 8 col-tiles).
// A staged via LDS from row-major bf16 s.

__global__ __launch_bounds__(256) void gemm_mfma(const short* __restrict__ s,
                                                 const short* __restrict__ Bf,
                                                 const float* __restrict__ bias,
                                                 float* __restrict__ C,
                                                 unsigned short* __restrict__ hb,
                                                 int N, int relu) {
    __shared__ short As[4096];                    // 4 kb x 128 rows x 8 = 8 KB
    __shared__ short Bs[4096];                    // 4 kb x 128 cols x 8 = 8 KB
    int t = threadIdx.x;
    int w = t >> 6, lane = t & 63;
    int lhi = lane >> 4, llo = lane & 15;
    int n0 = blockIdx.x * 128;
    int arow = t >> 1, ahalf = t & 1;
    int agn = n0 + arow;
    const short* arp = s + (size_t)agn * 1024 + ahalf * 16;
    short* adst = As + ((ahalf * 2) * 128 + arow) * 8;
    f32x4 acc[16] = {};                           // [rt*8 + ct]

    for (int c = 0; c < 32; c++) {
        // stage A: two 8-elem fragments per thread
        int4 a0v = {0, 0, 0, 0}, a1v = {0, 0, 0, 0};
        if (agn < N) {
            const int4* ap = (const int4*)(arp + c * 32);
            a0v = ap[0];
            a1v = ap[1];
        }
        *(int4*)adst              = a0v;
        *(int4*)(adst + 128 * 8)  = a1v;
        // stage B: 4 kb chunk, contiguous
        {
            const short* spb = Bf + (size_t)c * 4096 + t * 16;
            short* dp = Bs + t * 16;
            *(int4*)dp       = *(const int4*)spb;
            *(int4*)(dp + 8) = *(const int4*)(spb + 8);
        }
        __syncthreads();
        frag_t a0 = *(const frag_t*)(As + ((size_t)lhi * 128 + w * 32 + llo) * 8);
        frag_t a1 = *(const frag_t*)(As + ((size_t)lhi * 128 + w * 32 + llo + 16) * 8);
        #pragma unroll
        for (int ct = 0; ct < 8; ct++) {
            frag_t b = *(const frag_t*)(Bs + ((size_t)lhi * 128 + ct * 16 + llo) * 8);
            acc[ct]     = __builtin_amdgcn_mfma_f32_16x16x32_bf16(a0, b, acc[ct], 0, 0, 0);
            acc[8 + ct] = __builtin_amdgcn_mfma_f32_16x16x32_bf16(a1, b, acc[8 + ct], 0, 0, 0);
        }
        __syncthreads();
    }
    // epilogue: C/D layout col = llo, row = lhi*4 + reg
    #pragma unroll
    for (int rt = 0; rt < 2; rt++) {
        #pragma unroll
        for (int ct = 0; ct < 8; ct++) {
            int col = ct * 16 + llo;
            float bv = bias[col];
            #pragma unroll
            for (int rg = 0; rg < 4; rg++) {
                int rown = n0 + w * 32 + rt * 16 + lhi * 4 + rg;
                if (rown < N) {
                    float v = acc[rt * 8 + ct][rg] + bv;
                    if (relu) v = fmaxf(v, 0.f);
                    C[(size_t)rown * 128 + col] = v;
                    if (hb) hb[(size_t)rown * 128 + col] = (unsigned short)f2bf(v);
                }
            }
        }
    }
}

// ============================ launch ============================

extern "C" void kernel_launch(void* const* d_in, const int* in_sizes, int n_in,
                              void* d_out, int out_size, void* d_ws, size_t ws_size,
                              hipStream_t stream) {
    const float* z     = (const float*)d_in[0];
    const float* lin_w = (const float*)d_in[1];
    const float* lin_b = (const float*)d_in[2];
    const float* w1    = (const float*)d_in[3];
    const float* q1    = (const float*)d_in[4];
    const float* k1    = (const float*)d_in[5];
    const float* b1    = (const float*)d_in[6];
    const float* w2    = (const float*)d_in[7];
    const float* q2    = (const float*)d_in[8];
    const float* k2    = (const float*)d_in[9];
    const float* b2    = (const float*)d_in[10];
    const int*   ei    = (const int*)d_in[11];
    const int*   et    = (const int*)d_in[12];
    float* out = (float*)d_out;

    char* ws = (char*)d_ws;
    size_t off = 0;
    auto alloc = [&](size_t bytes) -> void* {
        void* p = ws + off;
        off += (bytes + 255) & ~(size_t)255;
        return p;
    };
    short* s     = (short*)alloc((size_t)N_NODES * 1024 * 2);   // 102.4 MB bf16 row-major
    float* h     = (float*)alloc((size_t)N_NODES * 128 * 4);    // 25.6 MB
    unsigned short* hb = (unsigned short*)alloc((size_t)N_NODES * 128 * 2);  // 12.8 MB
    float* Q     = (float*)alloc((size_t)N_NODES * 8 * 4);
    float* K     = (float*)alloc((size_t)N_NODES * 8 * 4);
    float* alpha = (float*)alloc((size_t)N_EDGES * 4);
    int* sorted  = (int*)alloc((size_t)N_EDGES * 4);
    int* deg8    = (int*)alloc((size_t)NSEG * 4);
    int* rowp8   = (int*)alloc((size_t)(NSEG + 1) * 4);
    int* cursor8 = (int*)alloc((size_t)NSEG * 4);
    int* part    = (int*)alloc(1024 * 4);
    float* wq    = (float*)alloc(8 * 128 * 4);
    float* wk    = (float*)alloc(8 * 128 * 4);
    short* Bf    = (short*)alloc((size_t)1024 * 128 * 2);       // 256 KB bf16 blocked

    const int* src = ei;
    const int* dst = ei + N_EDGES;

    const int M = NSEG;
    const int nparts = (M + 1023) / 1024;   // 391

    // CSR build over (dst,et)
    hipMemsetAsync(deg8, 0, (size_t)M * 4, stream);
    hist_kernel<<<(N_EDGES + 255) / 256, 256, 0, stream>>>(dst, et, deg8, N_EDGES);
    scan_part<<<nparts, 256, 0, stream>>>(deg8, part, M);
    scan_mid<<<1, 512, 0, stream>>>(part, nparts, rowp8, M);
    scan_fix<<<nparts, 256, 0, stream>>>(deg8, part, rowp8, cursor8, M);
    fill_kernel<<<(N_EDGES + 255) / 256, 256, 0, stream>>>(src, dst, et, cursor8, sorted, N_EDGES);

    // h = z @ lin_w.T + lin_b  (+ bf16 copy)
    gemm_lin<<<(N_NODES + 63) / 64, 256, 0, stream>>>(z, lin_w, lin_b, h, hb, N_NODES);

    int mgrid = (N_NODES + 127) / 128;   // 391

    // ---- layer 1: h -> h (relu)
    wconv_kernel<<<512, 256, 0, stream>>>(w1, Bf);
    wqk_kernel<<<8, 256, 0, stream>>>(w1, q1, k1, wq, wk);
    qk_table_kernel<<<(N_NODES + 3) / 4, 256, 0, stream>>>(h, wq, wk, Q, K, N_NODES);
    agg_s_kernel<<<N_NODES, 128, 0, stream>>>(hb, Q, K, rowp8, sorted, alpha, s, N_NODES);
    gemm_mfma<<<mgrid, 256, 0, stream>>>(s, Bf, b1, h, hb, N_NODES, 1);

    // ---- layer 2: h -> out (no relu)
    wconv_kernel<<<512, 256, 0, stream>>>(w2, Bf);
    wqk_kernel<<<8, 256, 0, stream>>>(w2, q2, k2, wq, wk);
    qk_table_kernel<<<(N_NODES + 3) / 4, 256, 0, stream>>>(h, wq, wk, Q, K, N_NODES);
    agg_s_kernel<<<N_NODES, 128, 0, stream>>>(hb, Q, K, rowp8, sorted, alpha, s, N_NODES);
    gemm_mfma<<<mgrid, 256, 0, stream>>>(s, Bf, b2, out, (unsigned short*)nullptr, N_NODES, 0);
}

// Round 5
// 559.911 us; speedup vs baseline: 1.9199x; 1.1077x over previous
//
#include <hip/hip_runtime.h>
#include <hip/hip_bf16.h>
#include <cstdint>
#include <cstddef>

#define N_NODES 50000
#define N_EDGES 800000
#define NSEG    (N_NODES * 8)            // 400000 (dst,et) buckets
#define LCAP    1024                     // max edges per node in the LDS fast path

using frag_t = __attribute__((ext_vector_type(8))) short;   // 8 bf16 (4 VGPRs)
using f32x4  = __attribute__((ext_vector_type(4))) float;   // 4 fp32 acc

__device__ __forceinline__ short f2bf(float x) {
    __hip_bfloat16 h = __float2bfloat16(x);
    return *reinterpret_cast<short*>(&h);
}
__device__ __forceinline__ float bf2f(unsigned short u) {
    union { unsigned int i; float f; } v;
    v.i = ((unsigned int)u) << 16;
    return v.f;
}

// ============================ CSR build over (dst*8 + et) ============================

__global__ void hist_kernel(const int* __restrict__ dst, const int* __restrict__ et,
                            int* __restrict__ deg8, int E) {
    int e = blockIdx.x * 256 + threadIdx.x;
    if (e < E) atomicAdd(&deg8[dst[e] * 8 + et[e]], 1);
}

__global__ __launch_bounds__(256) void scan_part(const int* __restrict__ deg8,
                                                 int* __restrict__ part, int M) {
    __shared__ int red[256];
    int t = threadIdx.x;
    int idx = blockIdx.x * 1024 + t * 4;
    int s = 0;
    if (idx + 3 < M) {
        int4 d = *(const int4*)(deg8 + idx);
        s = d.x + d.y + d.z + d.w;
    } else {
        for (int c = 0; c < 4; c++) if (idx + c < M) s += deg8[idx + c];
    }
    red[t] = s;
    __syncthreads();
    #pragma unroll
    for (int off = 128; off; off >>= 1) {
        if (t < off) red[t] += red[t + off];
        __syncthreads();
    }
    if (t == 0) part[blockIdx.x] = red[0];
}

__global__ __launch_bounds__(512) void scan_mid(int* __restrict__ part, int nparts,
                                                int* __restrict__ rowp, int M) {
    __shared__ int buf[512];
    int t = threadIdx.x;
    int own = (t < nparts) ? part[t] : 0;
    buf[t] = own;
    __syncthreads();
    for (int off = 1; off < 512; off <<= 1) {
        int v = buf[t];
        int u = (t >= off) ? buf[t - off] : 0;
        __syncthreads();
        buf[t] = v + u;
        __syncthreads();
    }
    if (t < nparts) part[t] = buf[t] - own;    // exclusive
    if (t == 511) rowp[M] = buf[511];          // total
}

__global__ __launch_bounds__(256) void scan_fix(const int* __restrict__ deg8,
                                                const int* __restrict__ part,
                                                int* __restrict__ rowp,
                                                int* __restrict__ cursor, int M) {
    __shared__ int wsum[4];
    int t = threadIdx.x, lane = t & 63, w = t >> 6;
    int idx = blockIdx.x * 1024 + t * 4;
    int v0 = 0, v1 = 0, v2 = 0, v3 = 0;
    if (idx + 3 < M) {
        int4 d = *(const int4*)(deg8 + idx);
        v0 = d.x; v1 = d.y; v2 = d.z; v3 = d.w;
    } else {
        if (idx     < M) v0 = deg8[idx];
        if (idx + 1 < M) v1 = deg8[idx + 1];
        if (idx + 2 < M) v2 = deg8[idx + 2];
        if (idx + 3 < M) v3 = deg8[idx + 3];
    }
    int tsum = v0 + v1 + v2 + v3;
    int sc = tsum;
    #pragma unroll
    for (int off = 1; off < 64; off <<= 1) {
        int u = __shfl_up(sc, off, 64);
        if (lane >= off) sc += u;
    }
    if (lane == 63) wsum[w] = sc;
    __syncthreads();
    int woff = 0;
    for (int i = 0; i < w; i++) woff += wsum[i];
    int excl = part[blockIdx.x] + woff + sc - tsum;
    if (idx     < M) { rowp[idx]     = excl; cursor[idx]     = excl; } excl += v0;
    if (idx + 1 < M) { rowp[idx + 1] = excl; cursor[idx + 1] = excl; } excl += v1;
    if (idx + 2 < M) { rowp[idx + 2] = excl; cursor[idx + 2] = excl; } excl += v2;
    if (idx + 3 < M) { rowp[idx + 3] = excl; cursor[idx + 3] = excl; }
}

__global__ void fill_kernel(const int* __restrict__ src, const int* __restrict__ dst,
                            const int* __restrict__ et, int* __restrict__ cursor,
                            int* __restrict__ sorted, int E) {
    int e = blockIdx.x * 256 + threadIdx.x;
    if (e < E) {
        int pos = atomicAdd(&cursor[dst[e] * 8 + et[e]], 1);
        sorted[pos] = src[e] | (et[e] << 16);
    }
}

// ============================ fp32 tiled GEMM (linear layer, K=64) ============================

__global__ __launch_bounds__(256) void gemm_lin(const float* __restrict__ A,
                                                const float* __restrict__ B,
                                                const float* __restrict__ bias,
                                                float* __restrict__ C,
                                                unsigned short* __restrict__ hb, int N) {
    const int Kdim = 64;
    __shared__ float As[32][64];
    __shared__ float Bs[32][128];
    int t = threadIdx.x;
    int n0 = blockIdx.x * 64;
    int rg = t >> 4, cg = t & 15;
    int an = t >> 2, ak = (t & 3) * 8;
    float acc[4][8] = {};

    for (int k0 = 0; k0 < Kdim; k0 += 32) {
        int gn = n0 + an;
        if (gn < N) {
            const float* ap = A + (size_t)gn * Kdim + k0 + ak;
            float4 v0 = *(const float4*)ap;
            float4 v1 = *(const float4*)(ap + 4);
            As[ak + 0][an] = v0.x; As[ak + 1][an] = v0.y;
            As[ak + 2][an] = v0.z; As[ak + 3][an] = v0.w;
            As[ak + 4][an] = v1.x; As[ak + 5][an] = v1.y;
            As[ak + 6][an] = v1.z; As[ak + 7][an] = v1.w;
        } else {
            #pragma unroll
            for (int c = 0; c < 8; c++) As[ak + c][an] = 0.f;
        }
        {
            int o = t >> 1, kh = (t & 1) * 16;
            const float* bp = B + (size_t)o * Kdim + k0 + kh;
            #pragma unroll
            for (int j = 0; j < 4; j++) {
                float4 v = ((const float4*)bp)[j];
                Bs[kh + j * 4 + 0][o] = v.x;
                Bs[kh + j * 4 + 1][o] = v.y;
                Bs[kh + j * 4 + 2][o] = v.z;
                Bs[kh + j * 4 + 3][o] = v.w;
            }
        }
        __syncthreads();
        #pragma unroll
        for (int k = 0; k < 32; k++) {
            float a[4], b[8];
            *(float4*)&a[0] = *(const float4*)&As[k][rg * 4];
            *(float4*)&b[0] = *(const float4*)&Bs[k][cg * 8];
            *(float4*)&b[4] = *(const float4*)&Bs[k][cg * 8 + 4];
            #pragma unroll
            for (int i = 0; i < 4; i++)
                #pragma unroll
                for (int j = 0; j < 8; j++)
                    acc[i][j] = fmaf(a[i], b[j], acc[i][j]);
        }
        __syncthreads();
    }
    #pragma unroll
    for (int i = 0; i < 4; i++) {
        int gn = n0 + rg * 4 + i;
        if (gn < N) {
            float v[8];
            unsigned short us[8];
            #pragma unroll
            for (int j = 0; j < 8; j++) {
                v[j] = acc[i][j] + bias[cg * 8 + j];
                us[j] = (unsigned short)f2bf(v[j]);
            }
            float* cp = C + (size_t)gn * 128 + cg * 8;
            *(float4*)cp       = *(float4*)&v[0];
            *(float4*)(cp + 4) = *(float4*)&v[4];
            *(int4*)(hb + (size_t)gn * 128 + cg * 8) = *(int4*)&us[0];
        }
    }
}

// ============================ W fp32 -> bf16 B-fragment-blocked ============================

__global__ void wconv_kernel(const float* __restrict__ W, short* __restrict__ Bf) {
    int idx = blockIdx.x * 256 + threadIdx.x;    // 131072
    int k = idx >> 7, o = idx & 127;
    float v = W[(size_t)k * 128 + o];
    Bf[(((size_t)(k >> 3) * 128) + o) * 8 + (k & 7)] = f2bf(v);
}

// ============================ wq = W@q, wk = W@k ============================

__global__ void wqk_kernel(const float* __restrict__ W, const float* __restrict__ q,
                           const float* __restrict__ k, float* __restrict__ wq,
                           float* __restrict__ wk) {
    int g = blockIdx.x * 256 + threadIdx.x;
    int which = g >> 10;
    int r = (g >> 7) & 7;
    int i = g & 127;
    const float* vec = which ? k : q;
    const float* wrow = W + ((size_t)r * 128 + i) * 128;
    float acc = 0.f;
    #pragma unroll 4
    for (int o = 0; o < 128; o++) acc = fmaf(wrow[o], vec[o], acc);
    (which ? wk : wq)[r * 128 + i] = acc;
}

// ============================ Q[n,r], K[n,r] tables (fp32 h) ============================

__global__ __launch_bounds__(256) void qk_table_kernel(const float* __restrict__ x,
                                                       const float* __restrict__ wq,
                                                       const float* __restrict__ wk,
                                                       float* __restrict__ Q,
                                                       float* __restrict__ K, int N) {
    int w = threadIdx.x >> 6, lane = threadIdx.x & 63;
    int n = blockIdx.x * 4 + w;
    if (n >= N) return;
    float x0 = x[(size_t)n * 128 + lane];
    float x1 = x[(size_t)n * 128 + 64 + lane];
    #pragma unroll
    for (int r = 0; r < 8; r++) {
        float pq = x0 * wq[r * 128 + lane] + x1 * wq[r * 128 + 64 + lane];
        float pk = x0 * wk[r * 128 + lane] + x1 * wk[r * 128 + 64 + lane];
        #pragma unroll
        for (int off = 32; off; off >>= 1) {
            pq += __shfl_xor(pq, off, 64);
            pk += __shfl_xor(pk, off, 64);
        }
        if (lane == 0) { Q[(size_t)n * 8 + r] = pq; K[(size_t)n * 8 + r] = pk; }
    }
}

// ============================ per-dst softmax + per-(dst,rel)-segment aggregate ============================
// LDS fast path: edge list + alpha staged in LDS; pass 3 walks all edges with
// 4-wide unrolled gathers, flushing the accumulator at relation boundaries.

__global__ __launch_bounds__(128) void agg_s_kernel(const unsigned short* __restrict__ hb,
                                                    const float* __restrict__ Q,
                                                    const float* __restrict__ Kt,
                                                    const int* __restrict__ rowp8,
                                                    const int* __restrict__ sorted,
                                                    float* __restrict__ alpha_g,
                                                    short* __restrict__ s, int N) {
    int n = blockIdx.x;
    int t = threadIdx.x;
    __shared__ int segs[9];
    __shared__ float qrow[8];
    __shared__ float red[128];
    __shared__ int   sidx[LCAP];
    __shared__ float salpha[LCAP];
    if (t < 9) segs[t] = rowp8[n * 8 + t];
    if (t < 8) qrow[t] = Q[(size_t)n * 8 + t];
    __syncthreads();
    int beg = segs[0], end = segs[8];
    int deg = end - beg;
    short* sp = s + (size_t)n * 1024;

    if (deg == 0) {
        int4 z = {0, 0, 0, 0};
        *(int4*)(sp + t * 8) = z;     // full 2 KB row of zeros
        return;
    }

    if (deg <= LCAP) {
        // ---- pass 1: stage indices, logits + max
        float lmax = -INFINITY;
        for (int j = t; j < deg; j += 128) {
            int pk = sorted[beg + j];
            sidx[j] = pk;
            int srcn = pk & 0xFFFF;
            int et = pk >> 16;
            float a = qrow[et] + Kt[(size_t)srcn * 8 + et];
            a = (a > 0.f) ? a : 0.2f * a;              // leaky_relu 0.2
            salpha[j] = a;
            lmax = fmaxf(lmax, a);
        }
        red[t] = lmax;
        __syncthreads();
        #pragma unroll
        for (int off = 64; off; off >>= 1) {
            if (t < off) red[t] = fmaxf(red[t], red[t + off]);
            __syncthreads();
        }
        float m = red[0];
        __syncthreads();
        // ---- pass 2: exp + denom
        float lsum = 0.f;
        for (int j = t; j < deg; j += 128) {
            float e = __expf(salpha[j] - m);
            salpha[j] = e;
            lsum += e;
        }
        red[t] = lsum;
        __syncthreads();
        #pragma unroll
        for (int off = 64; off; off >>= 1) {
            if (t < off) red[t] += red[t + off];
            __syncthreads();
        }
        float inv = 1.f / (red[0] + 1e-16f);
        __syncthreads();
        // ---- pass 3: walk all edges, 4 gathers in flight, flush at rel change
        float a = 0.f;
        int rcur = 0;
        int j = 0;
        for (; j + 4 <= deg; j += 4) {
            int p0 = sidx[j], p1 = sidx[j + 1], p2 = sidx[j + 2], p3 = sidx[j + 3];
            float x0 = bf2f(hb[(size_t)(p0 & 0xFFFF) * 128 + t]);
            float x1 = bf2f(hb[(size_t)(p1 & 0xFFFF) * 128 + t]);
            float x2 = bf2f(hb[(size_t)(p2 & 0xFFFF) * 128 + t]);
            float x3 = bf2f(hb[(size_t)(p3 & 0xFFFF) * 128 + t]);
            float w0 = salpha[j] * inv,     w1 = salpha[j + 1] * inv;
            float w2 = salpha[j + 2] * inv, w3 = salpha[j + 3] * inv;
            int e0 = p0 >> 16, e1 = p1 >> 16, e2 = p2 >> 16, e3 = p3 >> 16;
            while (rcur < e0) { sp[rcur * 128 + t] = f2bf(a); a = 0.f; rcur++; }
            a = fmaf(w0, x0, a);
            while (rcur < e1) { sp[rcur * 128 + t] = f2bf(a); a = 0.f; rcur++; }
            a = fmaf(w1, x1, a);
            while (rcur < e2) { sp[rcur * 128 + t] = f2bf(a); a = 0.f; rcur++; }
            a = fmaf(w2, x2, a);
            while (rcur < e3) { sp[rcur * 128 + t] = f2bf(a); a = 0.f; rcur++; }
            a = fmaf(w3, x3, a);
        }
        for (; j < deg; j++) {
            int p0 = sidx[j];
            float x0 = bf2f(hb[(size_t)(p0 & 0xFFFF) * 128 + t]);
            int e0 = p0 >> 16;
            while (rcur < e0) { sp[rcur * 128 + t] = f2bf(a); a = 0.f; rcur++; }
            a = fmaf(salpha[j] * inv, x0, a);
        }
        while (rcur < 8) { sp[rcur * 128 + t] = f2bf(a); a = 0.f; rcur++; }
        return;
    }

    // ---------- fallback (deg > LCAP): global alpha path ----------
    float lmax = -INFINITY;
    for (int j = beg + t; j < end; j += 128) {
        int pk = sorted[j];
        int srcn = pk & 0xFFFF;
        int et = pk >> 16;
        float a = qrow[et] + Kt[(size_t)srcn * 8 + et];
        a = (a > 0.f) ? a : 0.2f * a;
        alpha_g[j] = a;
        lmax = fmaxf(lmax, a);
    }
    red[t] = lmax;
    __syncthreads();
    #pragma unroll
    for (int off = 64; off; off >>= 1) {
        if (t < off) red[t] = fmaxf(red[t], red[t + off]);
        __syncthreads();
    }
    float m = red[0];
    __syncthreads();
    float lsum = 0.f;
    for (int j = beg + t; j < end; j += 128) {
        float e = __expf(alpha_g[j] - m);
        alpha_g[j] = e;
        lsum += e;
    }
    red[t] = lsum;
    __syncthreads();
    #pragma unroll
    for (int off = 64; off; off >>= 1) {
        if (t < off) red[t] += red[t + off];
        __syncthreads();
    }
    float inv = 1.f / (red[0] + 1e-16f);
    #pragma unroll 1
    for (int r = 0; r < 8; r++) {
        float a = 0.f;
        for (int j = segs[r]; j < segs[r + 1]; j++) {
            int srcn = sorted[j] & 0xFFFF;
            float x = bf2f(hb[(size_t)srcn * 128 + t]);
            a = fmaf(alpha_g[j] * inv, x, a);
        }
        sp[r * 128 + t] = f2bf(a);
    }
}

// ============================ MFMA GEMM: C[n,o] = s[n,:]@Bf + bias ============================

__global__ __launch_bounds__(256) void gemm_mfma(const short* __restrict__ s,
                                                 const short* __restrict__ Bf,
                                                 const float* __restrict__ bias,
                                                 float* __restrict__ C,
                                                 unsigned short* __restrict__ hb,
                                                 int N, int relu) {
    __shared__ short As[4096];                    // 4 kb x 128 rows x 8 = 8 KB
    __shared__ short Bs[4096];                    // 4 kb x 128 cols x 8 = 8 KB
    int t = threadIdx.x;
    int w = t >> 6, lane = t & 63;
    int lhi = lane >> 4, llo = lane & 15;
    int n0 = blockIdx.x * 128;
    int arow = t >> 1, ahalf = t & 1;
    int agn = n0 + arow;
    const short* arp = s + (size_t)agn * 1024 + ahalf * 16;
    short* adst = As + ((ahalf * 2) * 128 + arow) * 8;
    f32x4 acc[16] = {};                           // [rt*8 + ct]

    for (int c = 0; c < 32; c++) {
        int4 a0v = {0, 0, 0, 0}, a1v = {0, 0, 0, 0};
        if (agn < N) {
            const int4* ap = (const int4*)(arp + c * 32);
            a0v = ap[0];
            a1v = ap[1];
        }
        *(int4*)adst              = a0v;
        *(int4*)(adst + 128 * 8)  = a1v;
        {
            const short* spb = Bf + (size_t)c * 4096 + t * 16;
            short* dp = Bs + t * 16;
            *(int4*)dp       = *(const int4*)spb;
            *(int4*)(dp + 8) = *(const int4*)(spb + 8);
        }
        __syncthreads();
        frag_t a0 = *(const frag_t*)(As + ((size_t)lhi * 128 + w * 32 + llo) * 8);
        frag_t a1 = *(const frag_t*)(As + ((size_t)lhi * 128 + w * 32 + llo + 16) * 8);
        #pragma unroll
        for (int ct = 0; ct < 8; ct++) {
            frag_t b = *(const frag_t*)(Bs + ((size_t)lhi * 128 + ct * 16 + llo) * 8);
            acc[ct]     = __builtin_amdgcn_mfma_f32_16x16x32_bf16(a0, b, acc[ct], 0, 0, 0);
            acc[8 + ct] = __builtin_amdgcn_mfma_f32_16x16x32_bf16(a1, b, acc[8 + ct], 0, 0, 0);
        }
        __syncthreads();
    }
    #pragma unroll
    for (int rt = 0; rt < 2; rt++) {
        #pragma unroll
        for (int ct = 0; ct < 8; ct++) {
            int col = ct * 16 + llo;
            float bv = bias[col];
            #pragma unroll
            for (int rg = 0; rg < 4; rg++) {
                int rown = n0 + w * 32 + rt * 16 + lhi * 4 + rg;
                if (rown < N) {
                    float v = acc[rt * 8 + ct][rg] + bv;
                    if (relu) v = fmaxf(v, 0.f);
                    C[(size_t)rown * 128 + col] = v;
                    if (hb) hb[(size_t)rown * 128 + col] = (unsigned short)f2bf(v);
                }
            }
        }
    }
}

// ============================ launch ============================

extern "C" void kernel_launch(void* const* d_in, const int* in_sizes, int n_in,
                              void* d_out, int out_size, void* d_ws, size_t ws_size,
                              hipStream_t stream) {
    const float* z     = (const float*)d_in[0];
    const float* lin_w = (const float*)d_in[1];
    const float* lin_b = (const float*)d_in[2];
    const float* w1    = (const float*)d_in[3];
    const float* q1    = (const float*)d_in[4];
    const float* k1    = (const float*)d_in[5];
    const float* b1    = (const float*)d_in[6];
    const float* w2    = (const float*)d_in[7];
    const float* q2    = (const float*)d_in[8];
    const float* k2    = (const float*)d_in[9];
    const float* b2    = (const float*)d_in[10];
    const int*   ei    = (const int*)d_in[11];
    const int*   et    = (const int*)d_in[12];
    float* out = (float*)d_out;

    char* ws = (char*)d_ws;
    size_t off = 0;
    auto alloc = [&](size_t bytes) -> void* {
        void* p = ws + off;
        off += (bytes + 255) & ~(size_t)255;
        return p;
    };
    short* s     = (short*)alloc((size_t)N_NODES * 1024 * 2);   // 102.4 MB bf16 row-major
    float* h     = (float*)alloc((size_t)N_NODES * 128 * 4);    // 25.6 MB
    unsigned short* hb = (unsigned short*)alloc((size_t)N_NODES * 128 * 2);  // 12.8 MB
    float* Q     = (float*)alloc((size_t)N_NODES * 8 * 4);
    float* K     = (float*)alloc((size_t)N_NODES * 8 * 4);
    float* alpha = (float*)alloc((size_t)N_EDGES * 4);
    int* sorted  = (int*)alloc((size_t)N_EDGES * 4);
    int* deg8    = (int*)alloc((size_t)NSEG * 4);
    int* rowp8   = (int*)alloc((size_t)(NSEG + 1) * 4);
    int* cursor8 = (int*)alloc((size_t)NSEG * 4);
    int* part    = (int*)alloc(1024 * 4);
    float* wq    = (float*)alloc(8 * 128 * 4);
    float* wk    = (float*)alloc(8 * 128 * 4);
    short* Bf    = (short*)alloc((size_t)1024 * 128 * 2);       // 256 KB bf16 blocked

    const int* src = ei;
    const int* dst = ei + N_EDGES;

    const int M = NSEG;
    const int nparts = (M + 1023) / 1024;   // 391

    // CSR build over (dst,et)
    hipMemsetAsync(deg8, 0, (size_t)M * 4, stream);
    hist_kernel<<<(N_EDGES + 255) / 256, 256, 0, stream>>>(dst, et, deg8, N_EDGES);
    scan_part<<<nparts, 256, 0, stream>>>(deg8, part, M);
    scan_mid<<<1, 512, 0, stream>>>(part, nparts, rowp8, M);
    scan_fix<<<nparts, 256, 0, stream>>>(deg8, part, rowp8, cursor8, M);
    fill_kernel<<<(N_EDGES + 255) / 256, 256, 0, stream>>>(src, dst, et, cursor8, sorted, N_EDGES);

    // h = z @ lin_w.T + lin_b  (+ bf16 copy)
    gemm_lin<<<(N_NODES + 63) / 64, 256, 0, stream>>>(z, lin_w, lin_b, h, hb, N_NODES);

    int mgrid = (N_NODES + 127) / 128;   // 391

    // ---- layer 1: h -> h (relu)
    wconv_kernel<<<512, 256, 0, stream>>>(w1, Bf);
    wqk_kernel<<<8, 256, 0, stream>>>(w1, q1, k1, wq, wk);
    qk_table_kernel<<<(N_NODES + 3) / 4, 256, 0, stream>>>(h, wq, wk, Q, K, N_NODES);
    agg_s_kernel<<<N_NODES, 128, 0, stream>>>(hb, Q, K, rowp8, sorted, alpha, s, N_NODES);
    gemm_mfma<<<mgrid, 256, 0, stream>>>(s, Bf, b1, h, hb, N_NODES, 1);

    // ---- layer 2: h -> out (no relu)
    wconv_kernel<<<512, 256, 0, stream>>>(w2, Bf);
    wqk_kernel<<<8, 256, 0, stream>>>(w2, q2, k2, wq, wk);
    qk_table_kernel<<<(N_NODES + 3) / 4, 256, 0, stream>>>(h, wq, wk, Q, K, N_NODES);
    agg_s_kernel<<<N_NODES, 128, 0, stream>>>(hb, Q, K, rowp8, sorted, alpha, s, N_NODES);
    gemm_mfma<<<mgrid, 256, 0, stream>>>(s, Bf, b2, out, (unsigned short*)nullptr, N_NODES, 0);
}

// Round 6
// 484.368 us; speedup vs baseline: 2.2193x; 1.1560x over previous
//
#include <hip/hip_runtime.h>
#include <hip/hip_bf16.h>
#include <cstdint>
#include <cstddef>

#define N_NODES 50000
#define N_EDGES 800000
#define NSEG    (N_NODES * 8)            // 400000 (dst,et) buckets

using frag_t = __attribute__((ext_vector_type(8))) short;   // 8 bf16 (4 VGPRs)
using f32x4  = __attribute__((ext_vector_type(4))) float;   // 4 fp32 acc

__device__ __forceinline__ short f2bf(float x) {
    __hip_bfloat16 h = __float2bfloat16(x);
    return *reinterpret_cast<short*>(&h);
}
__device__ __forceinline__ float bf2f(unsigned int u) {   // low 16 bits = bf16
    union { unsigned int i; float f; } v;
    v.i = u << 16;
    return v.f;
}
__device__ __forceinline__ unsigned int packbf2(float lo, float hi) {
    unsigned int a = (unsigned short)f2bf(lo);
    unsigned int b = (unsigned short)f2bf(hi);
    return a | (b << 16);
}

// ============================ CSR build over (dst*8 + et) ============================

__global__ void hist_kernel(const int* __restrict__ dst, const int* __restrict__ et,
                            int* __restrict__ deg8, int E) {
    int e = blockIdx.x * 256 + threadIdx.x;
    if (e < E) atomicAdd(&deg8[dst[e] * 8 + et[e]], 1);
}

__global__ __launch_bounds__(256) void scan_part(const int* __restrict__ deg8,
                                                 int* __restrict__ part, int M) {
    __shared__ int red[256];
    int t = threadIdx.x;
    int idx = blockIdx.x * 1024 + t * 4;
    int s = 0;
    if (idx + 3 < M) {
        int4 d = *(const int4*)(deg8 + idx);
        s = d.x + d.y + d.z + d.w;
    } else {
        for (int c = 0; c < 4; c++) if (idx + c < M) s += deg8[idx + c];
    }
    red[t] = s;
    __syncthreads();
    #pragma unroll
    for (int off = 128; off; off >>= 1) {
        if (t < off) red[t] += red[t + off];
        __syncthreads();
    }
    if (t == 0) part[blockIdx.x] = red[0];
}

__global__ __launch_bounds__(512) void scan_mid(int* __restrict__ part, int nparts,
                                                int* __restrict__ rowp, int M) {
    __shared__ int buf[512];
    int t = threadIdx.x;
    int own = (t < nparts) ? part[t] : 0;
    buf[t] = own;
    __syncthreads();
    for (int off = 1; off < 512; off <<= 1) {
        int v = buf[t];
        int u = (t >= off) ? buf[t - off] : 0;
        __syncthreads();
        buf[t] = v + u;
        __syncthreads();
    }
    if (t < nparts) part[t] = buf[t] - own;    // exclusive
    if (t == 511) rowp[M] = buf[511];          // total
}

__global__ __launch_bounds__(256) void scan_fix(const int* __restrict__ deg8,
                                                const int* __restrict__ part,
                                                int* __restrict__ rowp,
                                                int* __restrict__ cursor, int M) {
    __shared__ int wsum[4];
    int t = threadIdx.x, lane = t & 63, w = t >> 6;
    int idx = blockIdx.x * 1024 + t * 4;
    int v0 = 0, v1 = 0, v2 = 0, v3 = 0;
    if (idx + 3 < M) {
        int4 d = *(const int4*)(deg8 + idx);
        v0 = d.x; v1 = d.y; v2 = d.z; v3 = d.w;
    } else {
        if (idx     < M) v0 = deg8[idx];
        if (idx + 1 < M) v1 = deg8[idx + 1];
        if (idx + 2 < M) v2 = deg8[idx + 2];
        if (idx + 3 < M) v3 = deg8[idx + 3];
    }
    int tsum = v0 + v1 + v2 + v3;
    int sc = tsum;
    #pragma unroll
    for (int off = 1; off < 64; off <<= 1) {
        int u = __shfl_up(sc, off, 64);
        if (lane >= off) sc += u;
    }
    if (lane == 63) wsum[w] = sc;
    __syncthreads();
    int woff = 0;
    for (int i = 0; i < w; i++) woff += wsum[i];
    int excl = part[blockIdx.x] + woff + sc - tsum;
    if (idx     < M) { rowp[idx]     = excl; cursor[idx]     = excl; } excl += v0;
    if (idx + 1 < M) { rowp[idx + 1] = excl; cursor[idx + 1] = excl; } excl += v1;
    if (idx + 2 < M) { rowp[idx + 2] = excl; cursor[idx + 2] = excl; } excl += v2;
    if (idx + 3 < M) { rowp[idx + 3] = excl; cursor[idx + 3] = excl; }
}

__global__ void fill_kernel(const int* __restrict__ src, const int* __restrict__ dst,
                            const int* __restrict__ et, int* __restrict__ cursor,
                            int* __restrict__ sorted, int E) {
    int e = blockIdx.x * 256 + threadIdx.x;
    if (e < E) {
        int pos = atomicAdd(&cursor[dst[e] * 8 + et[e]], 1);
        sorted[pos] = src[e] | (et[e] << 16);
    }
}

// ============================ fp32 tiled GEMM (linear layer, K=64) -> bf16 hb ============================

__global__ __launch_bounds__(256) void gemm_lin(const float* __restrict__ A,
                                                const float* __restrict__ B,
                                                const float* __restrict__ bias,
                                                unsigned short* __restrict__ hb, int N) {
    const int Kdim = 64;
    __shared__ float As[32][64];
    __shared__ float Bs[32][128];
    int t = threadIdx.x;
    int n0 = blockIdx.x * 64;
    int rg = t >> 4, cg = t & 15;
    int an = t >> 2, ak = (t & 3) * 8;
    float acc[4][8] = {};

    for (int k0 = 0; k0 < Kdim; k0 += 32) {
        int gn = n0 + an;
        if (gn < N) {
            const float* ap = A + (size_t)gn * Kdim + k0 + ak;
            float4 v0 = *(const float4*)ap;
            float4 v1 = *(const float4*)(ap + 4);
            As[ak + 0][an] = v0.x; As[ak + 1][an] = v0.y;
            As[ak + 2][an] = v0.z; As[ak + 3][an] = v0.w;
            As[ak + 4][an] = v1.x; As[ak + 5][an] = v1.y;
            As[ak + 6][an] = v1.z; As[ak + 7][an] = v1.w;
        } else {
            #pragma unroll
            for (int c = 0; c < 8; c++) As[ak + c][an] = 0.f;
        }
        {
            int o = t >> 1, kh = (t & 1) * 16;
            const float* bp = B + (size_t)o * Kdim + k0 + kh;
            #pragma unroll
            for (int j = 0; j < 4; j++) {
                float4 v = ((const float4*)bp)[j];
                Bs[kh + j * 4 + 0][o] = v.x;
                Bs[kh + j * 4 + 1][o] = v.y;
                Bs[kh + j * 4 + 2][o] = v.z;
                Bs[kh + j * 4 + 3][o] = v.w;
            }
        }
        __syncthreads();
        #pragma unroll
        for (int k = 0; k < 32; k++) {
            float a[4], b[8];
            *(float4*)&a[0] = *(const float4*)&As[k][rg * 4];
            *(float4*)&b[0] = *(const float4*)&Bs[k][cg * 8];
            *(float4*)&b[4] = *(const float4*)&Bs[k][cg * 8 + 4];
            #pragma unroll
            for (int i = 0; i < 4; i++)
                #pragma unroll
                for (int j = 0; j < 8; j++)
                    acc[i][j] = fmaf(a[i], b[j], acc[i][j]);
        }
        __syncthreads();
    }
    #pragma unroll
    for (int i = 0; i < 4; i++) {
        int gn = n0 + rg * 4 + i;
        if (gn < N) {
            unsigned short us[8];
            #pragma unroll
            for (int j = 0; j < 8; j++)
                us[j] = (unsigned short)f2bf(acc[i][j] + bias[cg * 8 + j]);
            *(int4*)(hb + (size_t)gn * 128 + cg * 8) = *(int4*)&us[0];
        }
    }
}

// ============================ W fp32 -> bf16 B-fragment-blocked ============================

__global__ void wconv_kernel(const float* __restrict__ W, short* __restrict__ Bf) {
    int idx = blockIdx.x * 256 + threadIdx.x;    // 131072
    int k = idx >> 7, o = idx & 127;
    float v = W[(size_t)k * 128 + o];
    Bf[(((size_t)(k >> 3) * 128) + o) * 8 + (k & 7)] = f2bf(v);
}

// ============================ wq = W@q, wk = W@k ============================

__global__ void wqk_kernel(const float* __restrict__ W, const float* __restrict__ q,
                           const float* __restrict__ k, float* __restrict__ wq,
                           float* __restrict__ wk) {
    int g = blockIdx.x * 256 + threadIdx.x;
    int which = g >> 10;
    int r = (g >> 7) & 7;
    int i = g & 127;
    const float* vec = which ? k : q;
    const float* wrow = W + ((size_t)r * 128 + i) * 128;
    float acc = 0.f;
    #pragma unroll 4
    for (int o = 0; o < 128; o++) acc = fmaf(wrow[o], vec[o], acc);
    (which ? wk : wq)[r * 128 + i] = acc;
}

// ============================ Q[n,r], K[n,r] tables (bf16 hb input) ============================

__global__ __launch_bounds__(256) void qk_table_kernel(const unsigned short* __restrict__ xb,
                                                       const float* __restrict__ wq,
                                                       const float* __restrict__ wk,
                                                       float* __restrict__ Q,
                                                       float* __restrict__ K, int N) {
    int w = threadIdx.x >> 6, lane = threadIdx.x & 63;
    int n = blockIdx.x * 4 + w;
    if (n >= N) return;
    unsigned int d = *(const unsigned int*)(xb + (size_t)n * 128 + lane * 2);
    float x0 = bf2f(d & 0xFFFF);
    float x1 = bf2f(d >> 16);
    #pragma unroll
    for (int r = 0; r < 8; r++) {
        float2 vq = *(const float2*)(wq + r * 128 + lane * 2);
        float2 vk = *(const float2*)(wk + r * 128 + lane * 2);
        float pq = x0 * vq.x + x1 * vq.y;
        float pk = x0 * vk.x + x1 * vk.y;
        #pragma unroll
        for (int off = 32; off; off >>= 1) {
            pq += __shfl_xor(pq, off, 64);
            pk += __shfl_xor(pk, off, 64);
        }
        if (lane == 0) { Q[(size_t)n * 8 + r] = pq; K[(size_t)n * 8 + r] = pk; }
    }
}

// ============================ wave-per-node softmax + aggregate ============================
// s[n*1024 + r*128 + c] = bf16( sum_{e in seg(n,r)} a_e * hb[src_e, c] )
// One 64-lane wave per node. No LDS, no barriers.

__global__ __launch_bounds__(256) void agg_s_kernel(const unsigned short* __restrict__ hb,
                                                    const float* __restrict__ Q,
                                                    const float* __restrict__ Kt,
                                                    const int* __restrict__ rowp8,
                                                    const int* __restrict__ sorted,
                                                    short* __restrict__ s, int N) {
    int wv = threadIdx.x >> 6;
    int lane = threadIdx.x & 63;
    int n = blockIdx.x * 4 + wv;
    if (n >= N) return;
    int beg = rowp8[n * 8];
    int end = rowp8[n * 8 + 8];
    int deg = end - beg;
    unsigned int* spw = (unsigned int*)(s + (size_t)n * 1024);   // 512 dwords
    const unsigned int* hbu = (const unsigned int*)hb;

    if (deg == 0) {
        int4 z = {0, 0, 0, 0};
        int4* p = (int4*)spw;        // 2048 B = 128 int4
        p[lane * 2]     = z;
        p[lane * 2 + 1] = z;
        return;
    }

    float2 acc = {0.f, 0.f};
    int rcur = 0;

    if (deg <= 64) {
        // ---- one edge per lane, register-resident softmax
        int pk = 0;
        float a = -INFINITY;
        if (lane < deg) {
            pk = sorted[beg + lane];
            int srcn = pk & 0xFFFF, etj = pk >> 16;
            a = Q[(size_t)n * 8 + etj] + Kt[(size_t)srcn * 8 + etj];
            a = (a > 0.f) ? a : 0.2f * a;                 // leaky_relu 0.2
        }
        float m = a;
        #pragma unroll
        for (int off = 32; off; off >>= 1) m = fmaxf(m, __shfl_xor(m, off, 64));
        float e = (lane < deg) ? __expf(a - m) : 0.f;
        float sum = e;
        #pragma unroll
        for (int off = 32; off; off >>= 1) sum += __shfl_xor(sum, off, 64);
        float w = e / (sum + 1e-16f);

        // ---- broadcast accumulate, 4-wide unrolled
        int j = 0;
        for (; j + 4 <= deg; j += 4) {
            int   p0 = __shfl(pk, j, 64),     p1 = __shfl(pk, j + 1, 64);
            int   p2 = __shfl(pk, j + 2, 64), p3 = __shfl(pk, j + 3, 64);
            float w0 = __shfl(w, j, 64),      w1 = __shfl(w, j + 1, 64);
            float w2 = __shfl(w, j + 2, 64),  w3 = __shfl(w, j + 3, 64);
            unsigned int d0 = hbu[(size_t)(p0 & 0xFFFF) * 64 + lane];
            unsigned int d1 = hbu[(size_t)(p1 & 0xFFFF) * 64 + lane];
            unsigned int d2 = hbu[(size_t)(p2 & 0xFFFF) * 64 + lane];
            unsigned int d3 = hbu[(size_t)(p3 & 0xFFFF) * 64 + lane];
            int e0 = p0 >> 16, e1 = p1 >> 16, e2 = p2 >> 16, e3 = p3 >> 16;
            while (rcur < e0) { spw[rcur * 64 + lane] = packbf2(acc.x, acc.y); acc.x = acc.y = 0.f; rcur++; }
            acc.x = fmaf(w0, bf2f(d0 & 0xFFFF), acc.x); acc.y = fmaf(w0, bf2f(d0 >> 16), acc.y);
            while (rcur < e1) { spw[rcur * 64 + lane] = packbf2(acc.x, acc.y); acc.x = acc.y = 0.f; rcur++; }
            acc.x = fmaf(w1, bf2f(d1 & 0xFFFF), acc.x); acc.y = fmaf(w1, bf2f(d1 >> 16), acc.y);
            while (rcur < e2) { spw[rcur * 64 + lane] = packbf2(acc.x, acc.y); acc.x = acc.y = 0.f; rcur++; }
            acc.x = fmaf(w2, bf2f(d2 & 0xFFFF), acc.x); acc.y = fmaf(w2, bf2f(d2 >> 16), acc.y);
            while (rcur < e3) { spw[rcur * 64 + lane] = packbf2(acc.x, acc.y); acc.x = acc.y = 0.f; rcur++; }
            acc.x = fmaf(w3, bf2f(d3 & 0xFFFF), acc.x); acc.y = fmaf(w3, bf2f(d3 >> 16), acc.y);
        }
        for (; j < deg; j++) {
            int   p0 = __shfl(pk, j, 64);
            float w0 = __shfl(w, j, 64);
            unsigned int d0 = hbu[(size_t)(p0 & 0xFFFF) * 64 + lane];
            int e0 = p0 >> 16;
            while (rcur < e0) { spw[rcur * 64 + lane] = packbf2(acc.x, acc.y); acc.x = acc.y = 0.f; rcur++; }
            acc.x = fmaf(w0, bf2f(d0 & 0xFFFF), acc.x); acc.y = fmaf(w0, bf2f(d0 >> 16), acc.y);
        }
        while (rcur < 8) { spw[rcur * 64 + lane] = packbf2(acc.x, acc.y); acc.x = acc.y = 0.f; rcur++; }
        return;
    }

    // ---------- generic path (deg > 64): chunked, logits recomputed per pass ----------
    auto logit = [&](int j) -> float {
        int pk = sorted[beg + j];
        int srcn = pk & 0xFFFF, etj = pk >> 16;
        float a = Q[(size_t)n * 8 + etj] + Kt[(size_t)srcn * 8 + etj];
        return (a > 0.f) ? a : 0.2f * a;
    };
    float m = -INFINITY;
    for (int j = lane; j < deg; j += 64) m = fmaxf(m, logit(j));
    #pragma unroll
    for (int off = 32; off; off >>= 1) m = fmaxf(m, __shfl_xor(m, off, 64));
    float sum = 0.f;
    for (int j = lane; j < deg; j += 64) sum += __expf(logit(j) - m);
    #pragma unroll
    for (int off = 32; off; off >>= 1) sum += __shfl_xor(sum, off, 64);
    float inv = 1.f / (sum + 1e-16f);

    for (int j0 = 0; j0 < deg; j0 += 64) {
        int cnt = min(64, deg - j0);
        int pk = 0;
        float w = 0.f;
        if (lane < cnt) {
            pk = sorted[beg + j0 + lane];
            int srcn = pk & 0xFFFF, etj = pk >> 16;
            float a = Q[(size_t)n * 8 + etj] + Kt[(size_t)srcn * 8 + etj];
            a = (a > 0.f) ? a : 0.2f * a;
            w = __expf(a - m) * inv;
        }
        for (int j = 0; j < cnt; j++) {
            int   p0 = __shfl(pk, j, 64);
            float w0 = __shfl(w, j, 64);
            unsigned int d0 = hbu[(size_t)(p0 & 0xFFFF) * 64 + lane];
            int e0 = p0 >> 16;
            while (rcur < e0) { spw[rcur * 64 + lane] = packbf2(acc.x, acc.y); acc.x = acc.y = 0.f; rcur++; }
            acc.x = fmaf(w0, bf2f(d0 & 0xFFFF), acc.x); acc.y = fmaf(w0, bf2f(d0 >> 16), acc.y);
        }
    }
    while (rcur < 8) { spw[rcur * 64 + lane] = packbf2(acc.x, acc.y); acc.x = acc.y = 0.f; rcur++; }
}

// ============================ MFMA GEMM: C[n,o] = s[n,:]@Bf + bias ============================

__global__ __launch_bounds__(256) void gemm_mfma(const short* __restrict__ s,
                                                 const short* __restrict__ Bf,
                                                 const float* __restrict__ bias,
                                                 float* __restrict__ Cout,
                                                 unsigned short* __restrict__ hbout,
                                                 int N, int relu) {
    __shared__ short As[4096];                    // 4 kb x 128 rows x 8 = 8 KB
    __shared__ short Bs[4096];                    // 4 kb x 128 cols x 8 = 8 KB
    int t = threadIdx.x;
    int w = t >> 6, lane = t & 63;
    int lhi = lane >> 4, llo = lane & 15;
    int n0 = blockIdx.x * 128;
    int arow = t >> 1, ahalf = t & 1;
    int agn = n0 + arow;
    const short* arp = s + (size_t)agn * 1024 + ahalf * 16;
    short* adst = As + ((ahalf * 2) * 128 + arow) * 8;
    f32x4 acc[16] = {};

    for (int c = 0; c < 32; c++) {
        int4 a0v = {0, 0, 0, 0}, a1v = {0, 0, 0, 0};
        if (agn < N) {
            const int4* ap = (const int4*)(arp + c * 32);
            a0v = ap[0];
            a1v = ap[1];
        }
        *(int4*)adst              = a0v;
        *(int4*)(adst + 128 * 8)  = a1v;
        {
            const short* spb = Bf + (size_t)c * 4096 + t * 16;
            short* dp = Bs + t * 16;
            *(int4*)dp       = *(const int4*)spb;
            *(int4*)(dp + 8) = *(const int4*)(spb + 8);
        }
        __syncthreads();
        frag_t a0 = *(const frag_t*)(As + ((size_t)lhi * 128 + w * 32 + llo) * 8);
        frag_t a1 = *(const frag_t*)(As + ((size_t)lhi * 128 + w * 32 + llo + 16) * 8);
        #pragma unroll
        for (int ct = 0; ct < 8; ct++) {
            frag_t b = *(const frag_t*)(Bs + ((size_t)lhi * 128 + ct * 16 + llo) * 8);
            acc[ct]     = __builtin_amdgcn_mfma_f32_16x16x32_bf16(a0, b, acc[ct], 0, 0, 0);
            acc[8 + ct] = __builtin_amdgcn_mfma_f32_16x16x32_bf16(a1, b, acc[8 + ct], 0, 0, 0);
        }
        __syncthreads();
    }
    #pragma unroll
    for (int rt = 0; rt < 2; rt++) {
        #pragma unroll
        for (int ct = 0; ct < 8; ct++) {
            int col = ct * 16 + llo;
            float bv = bias[col];
            #pragma unroll
            for (int rg = 0; rg < 4; rg++) {
                int rown = n0 + w * 32 + rt * 16 + lhi * 4 + rg;
                if (rown < N) {
                    float v = acc[rt * 8 + ct][rg] + bv;
                    if (relu) v = fmaxf(v, 0.f);
                    if (Cout)  Cout[(size_t)rown * 128 + col] = v;
                    if (hbout) hbout[(size_t)rown * 128 + col] = (unsigned short)f2bf(v);
                }
            }
        }
    }
}

// ============================ launch ============================

extern "C" void kernel_launch(void* const* d_in, const int* in_sizes, int n_in,
                              void* d_out, int out_size, void* d_ws, size_t ws_size,
                              hipStream_t stream) {
    const float* z     = (const float*)d_in[0];
    const float* lin_w = (const float*)d_in[1];
    const float* lin_b = (const float*)d_in[2];
    const float* w1    = (const float*)d_in[3];
    const float* q1    = (const float*)d_in[4];
    const float* k1    = (const float*)d_in[5];
    const float* b1    = (const float*)d_in[6];
    const float* w2    = (const float*)d_in[7];
    const float* q2    = (const float*)d_in[8];
    const float* k2    = (const float*)d_in[9];
    const float* b2    = (const float*)d_in[10];
    const int*   ei    = (const int*)d_in[11];
    const int*   et    = (const int*)d_in[12];
    float* out = (float*)d_out;

    char* ws = (char*)d_ws;
    size_t off = 0;
    auto alloc = [&](size_t bytes) -> void* {
        void* p = ws + off;
        off += (bytes + 255) & ~(size_t)255;
        return p;
    };
    short* s     = (short*)alloc((size_t)N_NODES * 1024 * 2);   // 102.4 MB bf16 row-major
    unsigned short* hb = (unsigned short*)alloc((size_t)N_NODES * 128 * 2);  // 12.8 MB
    float* Q     = (float*)alloc((size_t)N_NODES * 8 * 4);
    float* K     = (float*)alloc((size_t)N_NODES * 8 * 4);
    int* sorted  = (int*)alloc((size_t)N_EDGES * 4);
    int* deg8    = (int*)alloc((size_t)NSEG * 4);
    int* rowp8   = (int*)alloc((size_t)(NSEG + 1) * 4);
    int* cursor8 = (int*)alloc((size_t)NSEG * 4);
    int* part    = (int*)alloc(1024 * 4);
    float* wq    = (float*)alloc(8 * 128 * 4);
    float* wk    = (float*)alloc(8 * 128 * 4);
    short* Bf    = (short*)alloc((size_t)1024 * 128 * 2);       // 256 KB bf16 blocked

    const int* src = ei;
    const int* dst = ei + N_EDGES;

    const int M = NSEG;
    const int nparts = (M + 1023) / 1024;   // 391

    // CSR build over (dst,et)
    hipMemsetAsync(deg8, 0, (size_t)M * 4, stream);
    hist_kernel<<<(N_EDGES + 255) / 256, 256, 0, stream>>>(dst, et, deg8, N_EDGES);
    scan_part<<<nparts, 256, 0, stream>>>(deg8, part, M);
    scan_mid<<<1, 512, 0, stream>>>(part, nparts, rowp8, M);
    scan_fix<<<nparts, 256, 0, stream>>>(deg8, part, rowp8, cursor8, M);
    fill_kernel<<<(N_EDGES + 255) / 256, 256, 0, stream>>>(src, dst, et, cursor8, sorted, N_EDGES);

    // h = z @ lin_w.T + lin_b  (bf16 out only)
    gemm_lin<<<(N_NODES + 63) / 64, 256, 0, stream>>>(z, lin_w, lin_b, hb, N_NODES);

    int mgrid = (N_NODES + 127) / 128;   // 391
    int agrid = (N_NODES + 3) / 4;       // 12500

    // ---- layer 1: hb -> hb (relu)
    wconv_kernel<<<512, 256, 0, stream>>>(w1, Bf);
    wqk_kernel<<<8, 256, 0, stream>>>(w1, q1, k1, wq, wk);
    qk_table_kernel<<<agrid, 256, 0, stream>>>(hb, wq, wk, Q, K, N_NODES);
    agg_s_kernel<<<agrid, 256, 0, stream>>>(hb, Q, K, rowp8, sorted, s, N_NODES);
    gemm_mfma<<<mgrid, 256, 0, stream>>>(s, Bf, b1, (float*)nullptr, hb, N_NODES, 1);

    // ---- layer 2: hb -> out (no relu)
    wconv_kernel<<<512, 256, 0, stream>>>(w2, Bf);
    wqk_kernel<<<8, 256, 0, stream>>>(w2, q2, k2, wq, wk);
    qk_table_kernel<<<agrid, 256, 0, stream>>>(hb, wq, wk, Q, K, N_NODES);
    agg_s_kernel<<<agrid, 256, 0, stream>>>(hb, Q, K, rowp8, sorted, s, N_NODES);
    gemm_mfma<<<mgrid, 256, 0, stream>>>(s, Bf, b2, out, (unsigned short*)nullptr, N_NODES, 0);
}

// Round 7
// 414.908 us; speedup vs baseline: 2.5908x; 1.1674x over previous
//
#include <hip/hip_runtime.h>
#include <hip/hip_bf16.h>
#include <cstdint>
#include <cstddef>

#define N_NODES 50000
#define N_EDGES 800000
#define NSEG    (N_NODES * 8)            // 400000 (dst,et) buckets

using frag_t = __attribute__((ext_vector_type(8))) short;   // 8 bf16 (4 VGPRs)
using f32x4  = __attribute__((ext_vector_type(4))) float;   // 4 fp32 acc

__device__ __forceinline__ short f2bf(float x) {
    __hip_bfloat16 h = __float2bfloat16(x);
    return *reinterpret_cast<short*>(&h);
}
__device__ __forceinline__ float bf2f(unsigned int u) {   // low 16 bits = bf16
    union { unsigned int i; float f; } v;
    v.i = u << 16;
    return v.f;
}
__device__ __forceinline__ unsigned int packbf2(float lo, float hi) {
    unsigned int a = (unsigned short)f2bf(lo);
    unsigned int b = (unsigned short)f2bf(hi);
    return a | (b << 16);
}

// ============================ CSR build over (dst*8 + et) ============================

__global__ void hist_kernel(const int* __restrict__ dst, const int* __restrict__ et,
                            int* __restrict__ deg8, int E) {
    int e = blockIdx.x * 256 + threadIdx.x;
    if (e < E) atomicAdd(&deg8[dst[e] * 8 + et[e]], 1);
}

__global__ __launch_bounds__(256) void scan_part(const int* __restrict__ deg8,
                                                 int* __restrict__ part, int M) {
    __shared__ int red[256];
    int t = threadIdx.x;
    int idx = blockIdx.x * 1024 + t * 4;
    int s = 0;
    if (idx + 3 < M) {
        int4 d = *(const int4*)(deg8 + idx);
        s = d.x + d.y + d.z + d.w;
    } else {
        for (int c = 0; c < 4; c++) if (idx + c < M) s += deg8[idx + c];
    }
    red[t] = s;
    __syncthreads();
    #pragma unroll
    for (int off = 128; off; off >>= 1) {
        if (t < off) red[t] += red[t + off];
        __syncthreads();
    }
    if (t == 0) part[blockIdx.x] = red[0];
}

__global__ __launch_bounds__(512) void scan_mid(int* __restrict__ part, int nparts,
                                                int* __restrict__ rowp, int M) {
    __shared__ int buf[512];
    int t = threadIdx.x;
    int own = (t < nparts) ? part[t] : 0;
    buf[t] = own;
    __syncthreads();
    for (int off = 1; off < 512; off <<= 1) {
        int v = buf[t];
        int u = (t >= off) ? buf[t - off] : 0;
        __syncthreads();
        buf[t] = v + u;
        __syncthreads();
    }
    if (t < nparts) part[t] = buf[t] - own;    // exclusive
    if (t == 511) rowp[M] = buf[511];          // total
}

__global__ __launch_bounds__(256) void scan_fix(const int* __restrict__ deg8,
                                                const int* __restrict__ part,
                                                int* __restrict__ rowp,
                                                int* __restrict__ cursor, int M) {
    __shared__ int wsum[4];
    int t = threadIdx.x, lane = t & 63, w = t >> 6;
    int idx = blockIdx.x * 1024 + t * 4;
    int v0 = 0, v1 = 0, v2 = 0, v3 = 0;
    if (idx + 3 < M) {
        int4 d = *(const int4*)(deg8 + idx);
        v0 = d.x; v1 = d.y; v2 = d.z; v3 = d.w;
    } else {
        if (idx     < M) v0 = deg8[idx];
        if (idx + 1 < M) v1 = deg8[idx + 1];
        if (idx + 2 < M) v2 = deg8[idx + 2];
        if (idx + 3 < M) v3 = deg8[idx + 3];
    }
    int tsum = v0 + v1 + v2 + v3;
    int sc = tsum;
    #pragma unroll
    for (int off = 1; off < 64; off <<= 1) {
        int u = __shfl_up(sc, off, 64);
        if (lane >= off) sc += u;
    }
    if (lane == 63) wsum[w] = sc;
    __syncthreads();
    int woff = 0;
    for (int i = 0; i < w; i++) woff += wsum[i];
    int excl = part[blockIdx.x] + woff + sc - tsum;
    if (idx     < M) { rowp[idx]     = excl; cursor[idx]     = excl; } excl += v0;
    if (idx + 1 < M) { rowp[idx + 1] = excl; cursor[idx + 1] = excl; } excl += v1;
    if (idx + 2 < M) { rowp[idx + 2] = excl; cursor[idx + 2] = excl; } excl += v2;
    if (idx + 3 < M) { rowp[idx + 3] = excl; cursor[idx + 3] = excl; }
}

__global__ void fill_kernel(const int* __restrict__ src, const int* __restrict__ dst,
                            const int* __restrict__ et, int* __restrict__ cursor,
                            int* __restrict__ sorted, int E) {
    int e = blockIdx.x * 256 + threadIdx.x;
    if (e < E) {
        int pos = atomicAdd(&cursor[dst[e] * 8 + et[e]], 1);
        sorted[pos] = src[e] | (et[e] << 16);
    }
}

// ============================ fp32 tiled GEMM (linear layer, K=64) -> bf16 hb ============================

__global__ __launch_bounds__(256) void gemm_lin(const float* __restrict__ A,
                                                const float* __restrict__ B,
                                                const float* __restrict__ bias,
                                                unsigned short* __restrict__ hb, int N) {
    const int Kdim = 64;
    __shared__ float As[32][64];
    __shared__ float Bs[32][128];
    int t = threadIdx.x;
    int n0 = blockIdx.x * 64;
    int rg = t >> 4, cg = t & 15;
    int an = t >> 2, ak = (t & 3) * 8;
    float acc[4][8] = {};

    for (int k0 = 0; k0 < Kdim; k0 += 32) {
        int gn = n0 + an;
        if (gn < N) {
            const float* ap = A + (size_t)gn * Kdim + k0 + ak;
            float4 v0 = *(const float4*)ap;
            float4 v1 = *(const float4*)(ap + 4);
            As[ak + 0][an] = v0.x; As[ak + 1][an] = v0.y;
            As[ak + 2][an] = v0.z; As[ak + 3][an] = v0.w;
            As[ak + 4][an] = v1.x; As[ak + 5][an] = v1.y;
            As[ak + 6][an] = v1.z; As[ak + 7][an] = v1.w;
        } else {
            #pragma unroll
            for (int c = 0; c < 8; c++) As[ak + c][an] = 0.f;
        }
        {
            int o = t >> 1, kh = (t & 1) * 16;
            const float* bp = B + (size_t)o * Kdim + k0 + kh;
            #pragma unroll
            for (int j = 0; j < 4; j++) {
                float4 v = ((const float4*)bp)[j];
                Bs[kh + j * 4 + 0][o] = v.x;
                Bs[kh + j * 4 + 1][o] = v.y;
                Bs[kh + j * 4 + 2][o] = v.z;
                Bs[kh + j * 4 + 3][o] = v.w;
            }
        }
        __syncthreads();
        #pragma unroll
        for (int k = 0; k < 32; k++) {
            float a[4], b[8];
            *(float4*)&a[0] = *(const float4*)&As[k][rg * 4];
            *(float4*)&b[0] = *(const float4*)&Bs[k][cg * 8];
            *(float4*)&b[4] = *(const float4*)&Bs[k][cg * 8 + 4];
            #pragma unroll
            for (int i = 0; i < 4; i++)
                #pragma unroll
                for (int j = 0; j < 8; j++)
                    acc[i][j] = fmaf(a[i], b[j], acc[i][j]);
        }
        __syncthreads();
    }
    #pragma unroll
    for (int i = 0; i < 4; i++) {
        int gn = n0 + rg * 4 + i;
        if (gn < N) {
            unsigned short us[8];
            #pragma unroll
            for (int j = 0; j < 8; j++)
                us[j] = (unsigned short)f2bf(acc[i][j] + bias[cg * 8 + j]);
            *(int4*)(hb + (size_t)gn * 128 + cg * 8) = *(int4*)&us[0];
        }
    }
}

// ============================ W fp32 -> bf16 B-fragment-blocked ============================

__global__ void wconv_kernel(const float* __restrict__ W, short* __restrict__ Bf) {
    int idx = blockIdx.x * 256 + threadIdx.x;    // 131072
    int k = idx >> 7, o = idx & 127;
    float v = W[(size_t)k * 128 + o];
    Bf[(((size_t)(k >> 3) * 128) + o) * 8 + (k & 7)] = f2bf(v);
}

// ============================ wq = W@q, wk = W@k ============================

__global__ void wqk_kernel(const float* __restrict__ W, const float* __restrict__ q,
                           const float* __restrict__ k, float* __restrict__ wq,
                           float* __restrict__ wk) {
    int g = blockIdx.x * 256 + threadIdx.x;
    int which = g >> 10;
    int r = (g >> 7) & 7;
    int i = g & 127;
    const float* vec = which ? k : q;
    const float* wrow = W + ((size_t)r * 128 + i) * 128;
    float acc = 0.f;
    #pragma unroll 4
    for (int o = 0; o < 128; o++) acc = fmaf(wrow[o], vec[o], acc);
    (which ? wk : wq)[r * 128 + i] = acc;
}

// ============================ Q[n,r], K[n,r] tables: thread-per-node ============================
// 16 register accumulators; weight reads are wave-uniform -> s_load + SGPR-operand FMA.

__global__ __launch_bounds__(256) void qk_table_kernel(const unsigned short* __restrict__ xb,
                                                       const float* __restrict__ wq,
                                                       const float* __restrict__ wk,
                                                       float* __restrict__ Q,
                                                       float* __restrict__ K, int N) {
    int n = blockIdx.x * 256 + threadIdx.x;
    if (n >= N) return;
    const uint2* row = (const uint2*)(xb + (size_t)n * 128);
    float aq[8] = {}, ak[8] = {};
    for (int i = 0; i < 32; i++) {
        uint2 d = row[i];
        float x0 = bf2f(d.x & 0xFFFFu);
        float x1 = bf2f(d.x >> 16);
        float x2 = bf2f(d.y & 0xFFFFu);
        float x3 = bf2f(d.y >> 16);
        int c = i * 4;
        #pragma unroll
        for (int r = 0; r < 8; r++) {
            const float* wqr = wq + r * 128 + c;
            const float* wkr = wk + r * 128 + c;
            aq[r] = fmaf(x0, wqr[0], fmaf(x1, wqr[1], fmaf(x2, wqr[2], fmaf(x3, wqr[3], aq[r]))));
            ak[r] = fmaf(x0, wkr[0], fmaf(x1, wkr[1], fmaf(x2, wkr[2], fmaf(x3, wkr[3], ak[r]))));
        }
    }
    float4* qp = (float4*)(Q + (size_t)n * 8);
    qp[0] = *(float4*)&aq[0];
    qp[1] = *(float4*)&aq[4];
    float4* kp = (float4*)(K + (size_t)n * 8);
    kp[0] = *(float4*)&ak[0];
    kp[1] = *(float4*)&ak[4];
}

// ============================ wave-per-node softmax + aggregate ============================
// s[n*1024 + r*128 + c] = bf16( sum_{e in seg(n,r)} a_e * hb[src_e, c] )
// One 64-lane wave per node. No LDS, no barriers.

__global__ __launch_bounds__(256) void agg_s_kernel(const unsigned short* __restrict__ hb,
                                                    const float* __restrict__ Q,
                                                    const float* __restrict__ Kt,
                                                    const int* __restrict__ rowp8,
                                                    const int* __restrict__ sorted,
                                                    short* __restrict__ s, int N) {
    int wv = threadIdx.x >> 6;
    int lane = threadIdx.x & 63;
    int n = blockIdx.x * 4 + wv;
    if (n >= N) return;
    int beg = rowp8[n * 8];
    int end = rowp8[n * 8 + 8];
    int deg = end - beg;
    unsigned int* spw = (unsigned int*)(s + (size_t)n * 1024);   // 512 dwords
    const unsigned int* hbu = (const unsigned int*)hb;

    if (deg == 0) {
        int4 z = {0, 0, 0, 0};
        int4* p = (int4*)spw;        // 2048 B = 128 int4
        p[lane * 2]     = z;
        p[lane * 2 + 1] = z;
        return;
    }

    float2 acc = {0.f, 0.f};
    int rcur = 0;

    if (deg <= 64) {
        // ---- one edge per lane, register-resident softmax
        int pk = 0;
        float a = -INFINITY;
        if (lane < deg) {
            pk = sorted[beg + lane];
            int srcn = pk & 0xFFFF, etj = pk >> 16;
            a = Q[(size_t)n * 8 + etj] + Kt[(size_t)srcn * 8 + etj];
            a = (a > 0.f) ? a : 0.2f * a;                 // leaky_relu 0.2
        }
        float m = a;
        #pragma unroll
        for (int off = 32; off; off >>= 1) m = fmaxf(m, __shfl_xor(m, off, 64));
        float e = (lane < deg) ? __expf(a - m) : 0.f;
        float sum = e;
        #pragma unroll
        for (int off = 32; off; off >>= 1) sum += __shfl_xor(sum, off, 64);
        float w = e / (sum + 1e-16f);

        // ---- broadcast accumulate, 4-wide unrolled
        int j = 0;
        for (; j + 4 <= deg; j += 4) {
            int   p0 = __shfl(pk, j, 64),     p1 = __shfl(pk, j + 1, 64);
            int   p2 = __shfl(pk, j + 2, 64), p3 = __shfl(pk, j + 3, 64);
            float w0 = __shfl(w, j, 64),      w1 = __shfl(w, j + 1, 64);
            float w2 = __shfl(w, j + 2, 64),  w3 = __shfl(w, j + 3, 64);
            unsigned int d0 = hbu[(size_t)(p0 & 0xFFFF) * 64 + lane];
            unsigned int d1 = hbu[(size_t)(p1 & 0xFFFF) * 64 + lane];
            unsigned int d2 = hbu[(size_t)(p2 & 0xFFFF) * 64 + lane];
            unsigned int d3 = hbu[(size_t)(p3 & 0xFFFF) * 64 + lane];
            int e0 = p0 >> 16, e1 = p1 >> 16, e2 = p2 >> 16, e3 = p3 >> 16;
            while (rcur < e0) { spw[rcur * 64 + lane] = packbf2(acc.x, acc.y); acc.x = acc.y = 0.f; rcur++; }
            acc.x = fmaf(w0, bf2f(d0 & 0xFFFF), acc.x); acc.y = fmaf(w0, bf2f(d0 >> 16), acc.y);
            while (rcur < e1) { spw[rcur * 64 + lane] = packbf2(acc.x, acc.y); acc.x = acc.y = 0.f; rcur++; }
            acc.x = fmaf(w1, bf2f(d1 & 0xFFFF), acc.x); acc.y = fmaf(w1, bf2f(d1 >> 16), acc.y);
            while (rcur < e2) { spw[rcur * 64 + lane] = packbf2(acc.x, acc.y); acc.x = acc.y = 0.f; rcur++; }
            acc.x = fmaf(w2, bf2f(d2 & 0xFFFF), acc.x); acc.y = fmaf(w2, bf2f(d2 >> 16), acc.y);
            while (rcur < e3) { spw[rcur * 64 + lane] = packbf2(acc.x, acc.y); acc.x = acc.y = 0.f; rcur++; }
            acc.x = fmaf(w3, bf2f(d3 & 0xFFFF), acc.x); acc.y = fmaf(w3, bf2f(d3 >> 16), acc.y);
        }
        for (; j < deg; j++) {
            int   p0 = __shfl(pk, j, 64);
            float w0 = __shfl(w, j, 64);
            unsigned int d0 = hbu[(size_t)(p0 & 0xFFFF) * 64 + lane];
            int e0 = p0 >> 16;
            while (rcur < e0) { spw[rcur * 64 + lane] = packbf2(acc.x, acc.y); acc.x = acc.y = 0.f; rcur++; }
            acc.x = fmaf(w0, bf2f(d0 & 0xFFFF), acc.x); acc.y = fmaf(w0, bf2f(d0 >> 16), acc.y);
        }
        while (rcur < 8) { spw[rcur * 64 + lane] = packbf2(acc.x, acc.y); acc.x = acc.y = 0.f; rcur++; }
        return;
    }

    // ---------- generic path (deg > 64): chunked, logits recomputed per pass ----------
    auto logit = [&](int j) -> float {
        int pk = sorted[beg + j];
        int srcn = pk & 0xFFFF, etj = pk >> 16;
        float a = Q[(size_t)n * 8 + etj] + Kt[(size_t)srcn * 8 + etj];
        return (a > 0.f) ? a : 0.2f * a;
    };
    float m = -INFINITY;
    for (int j = lane; j < deg; j += 64) m = fmaxf(m, logit(j));
    #pragma unroll
    for (int off = 32; off; off >>= 1) m = fmaxf(m, __shfl_xor(m, off, 64));
    float sum = 0.f;
    for (int j = lane; j < deg; j += 64) sum += __expf(logit(j) - m);
    #pragma unroll
    for (int off = 32; off; off >>= 1) sum += __shfl_xor(sum, off, 64);
    float inv = 1.f / (sum + 1e-16f);

    for (int j0 = 0; j0 < deg; j0 += 64) {
        int cnt = min(64, deg - j0);
        int pk = 0;
        float w = 0.f;
        if (lane < cnt) {
            pk = sorted[beg + j0 + lane];
            int srcn = pk & 0xFFFF, etj = pk >> 16;
            float a = Q[(size_t)n * 8 + etj] + Kt[(size_t)srcn * 8 + etj];
            a = (a > 0.f) ? a : 0.2f * a;
            w = __expf(a - m) * inv;
        }
        for (int j = 0; j < cnt; j++) {
            int   p0 = __shfl(pk, j, 64);
            float w0 = __shfl(w, j, 64);
            unsigned int d0 = hbu[(size_t)(p0 & 0xFFFF) * 64 + lane];
            int e0 = p0 >> 16;
            while (rcur < e0) { spw[rcur * 64 + lane] = packbf2(acc.x, acc.y); acc.x = acc.y = 0.f; rcur++; }
            acc.x = fmaf(w0, bf2f(d0 & 0xFFFF), acc.x); acc.y = fmaf(w0, bf2f(d0 >> 16), acc.y);
        }
    }
    while (rcur < 8) { spw[rcur * 64 + lane] = packbf2(acc.x, acc.y); acc.x = acc.y = 0.f; rcur++; }
}

// ============================ MFMA GEMM: C[n,o] = s[n,:]@Bf + bias ============================

__global__ __launch_bounds__(256) void gemm_mfma(const short* __restrict__ s,
                                                 const short* __restrict__ Bf,
                                                 const float* __restrict__ bias,
                                                 float* __restrict__ Cout,
                                                 unsigned short* __restrict__ hbout,
                                                 int N, int relu) {
    __shared__ short As[4096];                    // 4 kb x 128 rows x 8 = 8 KB
    __shared__ short Bs[4096];                    // 4 kb x 128 cols x 8 = 8 KB
    int t = threadIdx.x;
    int w = t >> 6, lane = t & 63;
    int lhi = lane >> 4, llo = lane & 15;
    int n0 = blockIdx.x * 128;
    int arow = t >> 1, ahalf = t & 1;
    int agn = n0 + arow;
    const short* arp = s + (size_t)agn * 1024 + ahalf * 16;
    short* adst = As + ((ahalf * 2) * 128 + arow) * 8;
    f32x4 acc[16] = {};

    for (int c = 0; c < 32; c++) {
        int4 a0v = {0, 0, 0, 0}, a1v = {0, 0, 0, 0};
        if (agn < N) {
            const int4* ap = (const int4*)(arp + c * 32);
            a0v = ap[0];
            a1v = ap[1];
        }
        *(int4*)adst              = a0v;
        *(int4*)(adst + 128 * 8)  = a1v;
        {
            const short* spb = Bf + (size_t)c * 4096 + t * 16;
            short* dp = Bs + t * 16;
            *(int4*)dp       = *(const int4*)spb;
            *(int4*)(dp + 8) = *(const int4*)(spb + 8);
        }
        __syncthreads();
        frag_t a0 = *(const frag_t*)(As + ((size_t)lhi * 128 + w * 32 + llo) * 8);
        frag_t a1 = *(const frag_t*)(As + ((size_t)lhi * 128 + w * 32 + llo + 16) * 8);
        #pragma unroll
        for (int ct = 0; ct < 8; ct++) {
            frag_t b = *(const frag_t*)(Bs + ((size_t)lhi * 128 + ct * 16 + llo) * 8);
            acc[ct]     = __builtin_amdgcn_mfma_f32_16x16x32_bf16(a0, b, acc[ct], 0, 0, 0);
            acc[8 + ct] = __builtin_amdgcn_mfma_f32_16x16x32_bf16(a1, b, acc[8 + ct], 0, 0, 0);
        }
        __syncthreads();
    }
    #pragma unroll
    for (int rt = 0; rt < 2; rt++) {
        #pragma unroll
        for (int ct = 0; ct < 8; ct++) {
            int col = ct * 16 + llo;
            float bv = bias[col];
            #pragma unroll
            for (int rg = 0; rg < 4; rg++) {
                int rown = n0 + w * 32 + rt * 16 + lhi * 4 + rg;
                if (rown < N) {
                    float v = acc[rt * 8 + ct][rg] + bv;
                    if (relu) v = fmaxf(v, 0.f);
                    if (Cout)  Cout[(size_t)rown * 128 + col] = v;
                    if (hbout) hbout[(size_t)rown * 128 + col] = (unsigned short)f2bf(v);
                }
            }
        }
    }
}

// ============================ launch ============================

extern "C" void kernel_launch(void* const* d_in, const int* in_sizes, int n_in,
                              void* d_out, int out_size, void* d_ws, size_t ws_size,
                              hipStream_t stream) {
    const float* z     = (const float*)d_in[0];
    const float* lin_w = (const float*)d_in[1];
    const float* lin_b = (const float*)d_in[2];
    const float* w1    = (const float*)d_in[3];
    const float* q1    = (const float*)d_in[4];
    const float* k1    = (const float*)d_in[5];
    const float* b1    = (const float*)d_in[6];
    const float* w2    = (const float*)d_in[7];
    const float* q2    = (const float*)d_in[8];
    const float* k2    = (const float*)d_in[9];
    const float* b2    = (const float*)d_in[10];
    const int*   ei    = (const int*)d_in[11];
    const int*   et    = (const int*)d_in[12];
    float* out = (float*)d_out;

    char* ws = (char*)d_ws;
    size_t off = 0;
    auto alloc = [&](size_t bytes) -> void* {
        void* p = ws + off;
        off += (bytes + 255) & ~(size_t)255;
        return p;
    };
    short* s     = (short*)alloc((size_t)N_NODES * 1024 * 2);   // 102.4 MB bf16 row-major
    unsigned short* hb = (unsigned short*)alloc((size_t)N_NODES * 128 * 2);  // 12.8 MB
    float* Q     = (float*)alloc((size_t)N_NODES * 8 * 4);
    float* K     = (float*)alloc((size_t)N_NODES * 8 * 4);
    int* sorted  = (int*)alloc((size_t)N_EDGES * 4);
    int* deg8    = (int*)alloc((size_t)NSEG * 4);
    int* rowp8   = (int*)alloc((size_t)(NSEG + 1) * 4);
    int* cursor8 = (int*)alloc((size_t)NSEG * 4);
    int* part    = (int*)alloc(1024 * 4);
    float* wq    = (float*)alloc(8 * 128 * 4);
    float* wk    = (float*)alloc(8 * 128 * 4);
    short* Bf    = (short*)alloc((size_t)1024 * 128 * 2);       // 256 KB bf16 blocked

    const int* src = ei;
    const int* dst = ei + N_EDGES;

    const int M = NSEG;
    const int nparts = (M + 1023) / 1024;   // 391

    // CSR build over (dst,et)
    hipMemsetAsync(deg8, 0, (size_t)M * 4, stream);
    hist_kernel<<<(N_EDGES + 255) / 256, 256, 0, stream>>>(dst, et, deg8, N_EDGES);
    scan_part<<<nparts, 256, 0, stream>>>(deg8, part, M);
    scan_mid<<<1, 512, 0, stream>>>(part, nparts, rowp8, M);
    scan_fix<<<nparts, 256, 0, stream>>>(deg8, part, rowp8, cursor8, M);
    fill_kernel<<<(N_EDGES + 255) / 256, 256, 0, stream>>>(src, dst, et, cursor8, sorted, N_EDGES);

    // h = z @ lin_w.T + lin_b  (bf16 out only)
    gemm_lin<<<(N_NODES + 63) / 64, 256, 0, stream>>>(z, lin_w, lin_b, hb, N_NODES);

    int mgrid = (N_NODES + 127) / 128;   // 391
    int agrid = (N_NODES + 3) / 4;       // 12500
    int qgrid = (N_NODES + 255) / 256;   // 196

    // ---- layer 1: hb -> hb (relu)
    wconv_kernel<<<512, 256, 0, stream>>>(w1, Bf);
    wqk_kernel<<<8, 256, 0, stream>>>(w1, q1, k1, wq, wk);
    qk_table_kernel<<<qgrid, 256, 0, stream>>>(hb, wq, wk, Q, K, N_NODES);
    agg_s_kernel<<<agrid, 256, 0, stream>>>(hb, Q, K, rowp8, sorted, s, N_NODES);
    gemm_mfma<<<mgrid, 256, 0, stream>>>(s, Bf, b1, (float*)nullptr, hb, N_NODES, 1);

    // ---- layer 2: hb -> out (no relu)
    wconv_kernel<<<512, 256, 0, stream>>>(w2, Bf);
    wqk_kernel<<<8, 256, 0, stream>>>(w2, q2, k2, wq, wk);
    qk_table_kernel<<<qgrid, 256, 0, stream>>>(hb, wq, wk, Q, K, N_NODES);
    agg_s_kernel<<<agrid, 256, 0, stream>>>(hb, Q, K, rowp8, sorted, s, N_NODES);
    gemm_mfma<<<mgrid, 256, 0, stream>>>(s, Bf, b2, out, (unsigned short*)nullptr, N_NODES, 0);
}

// Round 8
// 411.324 us; speedup vs baseline: 2.6134x; 1.0087x over previous
//
#include <hip/hip_runtime.h>
#include <hip/hip_bf16.h>
#include <cstdint>
#include <cstddef>

#define N_NODES 50000
#define N_EDGES 800000
#define NSEG    (N_NODES * 8)            // 400000 (dst,et) buckets

using frag_t = __attribute__((ext_vector_type(8))) short;   // 8 bf16 (4 VGPRs)
using f32x4  = __attribute__((ext_vector_type(4))) float;   // 4 fp32 acc

typedef const __attribute__((address_space(1))) void* gptr_t;
typedef __attribute__((address_space(3))) void* lptr_t;

__device__ __forceinline__ short f2bf(float x) {
    __hip_bfloat16 h = __float2bfloat16(x);
    return *reinterpret_cast<short*>(&h);
}
__device__ __forceinline__ float bf2f(unsigned int u) {   // low 16 bits = bf16
    union { unsigned int i; float f; } v;
    v.i = u << 16;
    return v.f;
}
__device__ __forceinline__ unsigned int packbf2(float lo, float hi) {
    unsigned int a = (unsigned short)f2bf(lo);
    unsigned int b = (unsigned short)f2bf(hi);
    return a | (b << 16);
}

// ============================ CSR build over (dst*8 + et) ============================

__global__ void hist_kernel(const int* __restrict__ dst, const int* __restrict__ et,
                            int* __restrict__ deg8, int E) {
    int e = blockIdx.x * 256 + threadIdx.x;
    if (e < E) atomicAdd(&deg8[dst[e] * 8 + et[e]], 1);
}

__global__ __launch_bounds__(256) void scan_part(const int* __restrict__ deg8,
                                                 int* __restrict__ part, int M) {
    __shared__ int red[256];
    int t = threadIdx.x;
    int idx = blockIdx.x * 1024 + t * 4;
    int s = 0;
    if (idx + 3 < M) {
        int4 d = *(const int4*)(deg8 + idx);
        s = d.x + d.y + d.z + d.w;
    } else {
        for (int c = 0; c < 4; c++) if (idx + c < M) s += deg8[idx + c];
    }
    red[t] = s;
    __syncthreads();
    #pragma unroll
    for (int off = 128; off; off >>= 1) {
        if (t < off) red[t] += red[t + off];
        __syncthreads();
    }
    if (t == 0) part[blockIdx.x] = red[0];
}

__global__ __launch_bounds__(512) void scan_mid(int* __restrict__ part, int nparts,
                                                int* __restrict__ rowp, int M) {
    __shared__ int buf[512];
    int t = threadIdx.x;
    int own = (t < nparts) ? part[t] : 0;
    buf[t] = own;
    __syncthreads();
    for (int off = 1; off < 512; off <<= 1) {
        int v = buf[t];
        int u = (t >= off) ? buf[t - off] : 0;
        __syncthreads();
        buf[t] = v + u;
        __syncthreads();
    }
    if (t < nparts) part[t] = buf[t] - own;    // exclusive
    if (t == 511) rowp[M] = buf[511];          // total
}

__global__ __launch_bounds__(256) void scan_fix(const int* __restrict__ deg8,
                                                const int* __restrict__ part,
                                                int* __restrict__ rowp,
                                                int* __restrict__ cursor, int M) {
    __shared__ int wsum[4];
    int t = threadIdx.x, lane = t & 63, w = t >> 6;
    int idx = blockIdx.x * 1024 + t * 4;
    int v0 = 0, v1 = 0, v2 = 0, v3 = 0;
    if (idx + 3 < M) {
        int4 d = *(const int4*)(deg8 + idx);
        v0 = d.x; v1 = d.y; v2 = d.z; v3 = d.w;
    } else {
        if (idx     < M) v0 = deg8[idx];
        if (idx + 1 < M) v1 = deg8[idx + 1];
        if (idx + 2 < M) v2 = deg8[idx + 2];
        if (idx + 3 < M) v3 = deg8[idx + 3];
    }
    int tsum = v0 + v1 + v2 + v3;
    int sc = tsum;
    #pragma unroll
    for (int off = 1; off < 64; off <<= 1) {
        int u = __shfl_up(sc, off, 64);
        if (lane >= off) sc += u;
    }
    if (lane == 63) wsum[w] = sc;
    __syncthreads();
    int woff = 0;
    for (int i = 0; i < w; i++) woff += wsum[i];
    int excl = part[blockIdx.x] + woff + sc - tsum;
    if (idx     < M) { rowp[idx]     = excl; cursor[idx]     = excl; } excl += v0;
    if (idx + 1 < M) { rowp[idx + 1] = excl; cursor[idx + 1] = excl; } excl += v1;
    if (idx + 2 < M) { rowp[idx + 2] = excl; cursor[idx + 2] = excl; } excl += v2;
    if (idx + 3 < M) { rowp[idx + 3] = excl; cursor[idx + 3] = excl; }
}

__global__ void fill_kernel(const int* __restrict__ src, const int* __restrict__ dst,
                            const int* __restrict__ et, int* __restrict__ cursor,
                            int* __restrict__ sorted, int E) {
    int e = blockIdx.x * 256 + threadIdx.x;
    if (e < E) {
        int pos = atomicAdd(&cursor[dst[e] * 8 + et[e]], 1);
        sorted[pos] = src[e] | (et[e] << 16);
    }
}

// ============================ fp32 tiled GEMM (linear layer, K=64) -> bf16 hb ============================

__global__ __launch_bounds__(256) void gemm_lin(const float* __restrict__ A,
                                                const float* __restrict__ B,
                                                const float* __restrict__ bias,
                                                unsigned short* __restrict__ hb, int N) {
    const int Kdim = 64;
    __shared__ float As[32][64];
    __shared__ float Bs[32][128];
    int t = threadIdx.x;
    int n0 = blockIdx.x * 64;
    int rg = t >> 4, cg = t & 15;
    int an = t >> 2, ak = (t & 3) * 8;
    float acc[4][8] = {};

    for (int k0 = 0; k0 < Kdim; k0 += 32) {
        int gn = n0 + an;
        if (gn < N) {
            const float* ap = A + (size_t)gn * Kdim + k0 + ak;
            float4 v0 = *(const float4*)ap;
            float4 v1 = *(const float4*)(ap + 4);
            As[ak + 0][an] = v0.x; As[ak + 1][an] = v0.y;
            As[ak + 2][an] = v0.z; As[ak + 3][an] = v0.w;
            As[ak + 4][an] = v1.x; As[ak + 5][an] = v1.y;
            As[ak + 6][an] = v1.z; As[ak + 7][an] = v1.w;
        } else {
            #pragma unroll
            for (int c = 0; c < 8; c++) As[ak + c][an] = 0.f;
        }
        {
            int o = t >> 1, kh = (t & 1) * 16;
            const float* bp = B + (size_t)o * Kdim + k0 + kh;
            #pragma unroll
            for (int j = 0; j < 4; j++) {
                float4 v = ((const float4*)bp)[j];
                Bs[kh + j * 4 + 0][o] = v.x;
                Bs[kh + j * 4 + 1][o] = v.y;
                Bs[kh + j * 4 + 2][o] = v.z;
                Bs[kh + j * 4 + 3][o] = v.w;
            }
        }
        __syncthreads();
        #pragma unroll
        for (int k = 0; k < 32; k++) {
            float a[4], b[8];
            *(float4*)&a[0] = *(const float4*)&As[k][rg * 4];
            *(float4*)&b[0] = *(const float4*)&Bs[k][cg * 8];
            *(float4*)&b[4] = *(const float4*)&Bs[k][cg * 8 + 4];
            #pragma unroll
            for (int i = 0; i < 4; i++)
                #pragma unroll
                for (int j = 0; j < 8; j++)
                    acc[i][j] = fmaf(a[i], b[j], acc[i][j]);
        }
        __syncthreads();
    }
    #pragma unroll
    for (int i = 0; i < 4; i++) {
        int gn = n0 + rg * 4 + i;
        if (gn < N) {
            unsigned short us[8];
            #pragma unroll
            for (int j = 0; j < 8; j++)
                us[j] = (unsigned short)f2bf(acc[i][j] + bias[cg * 8 + j]);
            *(int4*)(hb + (size_t)gn * 128 + cg * 8) = *(int4*)&us[0];
        }
    }
}

// ============================ merged W prep: Bf convert + wq/wk ============================
// g in [0, 131072): Bf[(k>>3)*128*8 + o*8 + (k&7)] = bf16(W[k*128+o])
// g in [131072, 133120): wq/wk dot products

__global__ void wprep_kernel(const float* __restrict__ W, const float* __restrict__ q,
                             const float* __restrict__ k, short* __restrict__ Bf,
                             float* __restrict__ wq, float* __restrict__ wk) {
    int g = blockIdx.x * 256 + threadIdx.x;
    if (g < 131072) {
        int kk = g >> 7, o = g & 127;
        float v = W[(size_t)kk * 128 + o];
        Bf[(((size_t)(kk >> 3) * 128) + o) * 8 + (kk & 7)] = f2bf(v);
        return;
    }
    int h = g - 131072;
    if (h < 2048) {
        int which = h >> 10;
        int r = (h >> 7) & 7;
        int i = h & 127;
        const float* vec = which ? k : q;
        const float* wrow = W + ((size_t)r * 128 + i) * 128;
        float acc = 0.f;
        #pragma unroll 4
        for (int o = 0; o < 128; o++) acc = fmaf(wrow[o], vec[o], acc);
        (which ? wk : wq)[r * 128 + i] = acc;
    }
}

// ============================ Q[n,r], K[n,r] tables: thread-per-node ============================

__global__ __launch_bounds__(256) void qk_table_kernel(const unsigned short* __restrict__ xb,
                                                       const float* __restrict__ wq,
                                                       const float* __restrict__ wk,
                                                       float* __restrict__ Q,
                                                       float* __restrict__ K, int N) {
    int n = blockIdx.x * 256 + threadIdx.x;
    if (n >= N) return;
    const uint2* row = (const uint2*)(xb + (size_t)n * 128);
    float aq[8] = {}, ak[8] = {};
    for (int i = 0; i < 32; i++) {
        uint2 d = row[i];
        float x0 = bf2f(d.x & 0xFFFFu);
        float x1 = bf2f(d.x >> 16);
        float x2 = bf2f(d.y & 0xFFFFu);
        float x3 = bf2f(d.y >> 16);
        int c = i * 4;
        #pragma unroll
        for (int r = 0; r < 8; r++) {
            const float* wqr = wq + r * 128 + c;
            const float* wkr = wk + r * 128 + c;
            aq[r] = fmaf(x0, wqr[0], fmaf(x1, wqr[1], fmaf(x2, wqr[2], fmaf(x3, wqr[3], aq[r]))));
            ak[r] = fmaf(x0, wkr[0], fmaf(x1, wkr[1], fmaf(x2, wkr[2], fmaf(x3, wkr[3], ak[r]))));
        }
    }
    float4* qp = (float4*)(Q + (size_t)n * 8);
    qp[0] = *(float4*)&aq[0];
    qp[1] = *(float4*)&aq[4];
    float4* kp = (float4*)(K + (size_t)n * 8);
    kp[0] = *(float4*)&ak[0];
    kp[1] = *(float4*)&ak[4];
}

// ============================ wave-per-node softmax + aggregate ============================
// 8-wide unrolled gathers for memory-level parallelism.

__global__ __launch_bounds__(256) void agg_s_kernel(const unsigned short* __restrict__ hb,
                                                    const float* __restrict__ Q,
                                                    const float* __restrict__ Kt,
                                                    const int* __restrict__ rowp8,
                                                    const int* __restrict__ sorted,
                                                    short* __restrict__ s, int N) {
    int wv = threadIdx.x >> 6;
    int lane = threadIdx.x & 63;
    int n = blockIdx.x * 4 + wv;
    if (n >= N) return;
    int beg = rowp8[n * 8];
    int end = rowp8[n * 8 + 8];
    int deg = end - beg;
    unsigned int* spw = (unsigned int*)(s + (size_t)n * 1024);   // 512 dwords
    const unsigned int* hbu = (const unsigned int*)hb;

    if (deg == 0) {
        int4 z = {0, 0, 0, 0};
        int4* p = (int4*)spw;
        p[lane * 2]     = z;
        p[lane * 2 + 1] = z;
        return;
    }

    float2 acc = {0.f, 0.f};
    int rcur = 0;

    if (deg <= 64) {
        int pk = 0;
        float a = -INFINITY;
        if (lane < deg) {
            pk = sorted[beg + lane];
            int srcn = pk & 0xFFFF, etj = pk >> 16;
            a = Q[(size_t)n * 8 + etj] + Kt[(size_t)srcn * 8 + etj];
            a = (a > 0.f) ? a : 0.2f * a;                 // leaky_relu 0.2
        }
        float m = a;
        #pragma unroll
        for (int off = 32; off; off >>= 1) m = fmaxf(m, __shfl_xor(m, off, 64));
        float e = (lane < deg) ? __expf(a - m) : 0.f;
        float sum = e;
        #pragma unroll
        for (int off = 32; off; off >>= 1) sum += __shfl_xor(sum, off, 64);
        float w = e / (sum + 1e-16f);

        // ---- broadcast accumulate, 8 gathers in flight
        int j = 0;
        for (; j + 8 <= deg; j += 8) {
            int pp[8]; float ww[8]; unsigned int dd[8];
            #pragma unroll
            for (int i = 0; i < 8; i++) {
                pp[i] = __shfl(pk, j + i, 64);
                ww[i] = __shfl(w,  j + i, 64);
            }
            #pragma unroll
            for (int i = 0; i < 8; i++)
                dd[i] = hbu[(size_t)(pp[i] & 0xFFFF) * 64 + lane];
            #pragma unroll
            for (int i = 0; i < 8; i++) {
                int e0 = pp[i] >> 16;
                while (rcur < e0) { spw[rcur * 64 + lane] = packbf2(acc.x, acc.y); acc.x = acc.y = 0.f; rcur++; }
                acc.x = fmaf(ww[i], bf2f(dd[i] & 0xFFFF), acc.x);
                acc.y = fmaf(ww[i], bf2f(dd[i] >> 16),    acc.y);
            }
        }
        for (; j < deg; j++) {
            int   p0 = __shfl(pk, j, 64);
            float w0 = __shfl(w, j, 64);
            unsigned int d0 = hbu[(size_t)(p0 & 0xFFFF) * 64 + lane];
            int e0 = p0 >> 16;
            while (rcur < e0) { spw[rcur * 64 + lane] = packbf2(acc.x, acc.y); acc.x = acc.y = 0.f; rcur++; }
            acc.x = fmaf(w0, bf2f(d0 & 0xFFFF), acc.x);
            acc.y = fmaf(w0, bf2f(d0 >> 16),    acc.y);
        }
        while (rcur < 8) { spw[rcur * 64 + lane] = packbf2(acc.x, acc.y); acc.x = acc.y = 0.f; rcur++; }
        return;
    }

    // ---------- generic path (deg > 64): chunked, logits recomputed per pass ----------
    auto logit = [&](int j) -> float {
        int pk = sorted[beg + j];
        int srcn = pk & 0xFFFF, etj = pk >> 16;
        float a = Q[(size_t)n * 8 + etj] + Kt[(size_t)srcn * 8 + etj];
        return (a > 0.f) ? a : 0.2f * a;
    };
    float m = -INFINITY;
    for (int j = lane; j < deg; j += 64) m = fmaxf(m, logit(j));
    #pragma unroll
    for (int off = 32; off; off >>= 1) m = fmaxf(m, __shfl_xor(m, off, 64));
    float sum = 0.f;
    for (int j = lane; j < deg; j += 64) sum += __expf(logit(j) - m);
    #pragma unroll
    for (int off = 32; off; off >>= 1) sum += __shfl_xor(sum, off, 64);
    float inv = 1.f / (sum + 1e-16f);

    for (int j0 = 0; j0 < deg; j0 += 64) {
        int cnt = min(64, deg - j0);
        int pk = 0;
        float w = 0.f;
        if (lane < cnt) {
            pk = sorted[beg + j0 + lane];
            int srcn = pk & 0xFFFF, etj = pk >> 16;
            float a = Q[(size_t)n * 8 + etj] + Kt[(size_t)srcn * 8 + etj];
            a = (a > 0.f) ? a : 0.2f * a;
            w = __expf(a - m) * inv;
        }
        for (int j = 0; j < cnt; j++) {
            int   p0 = __shfl(pk, j, 64);
            float w0 = __shfl(w, j, 64);
            unsigned int d0 = hbu[(size_t)(p0 & 0xFFFF) * 64 + lane];
            int e0 = p0 >> 16;
            while (rcur < e0) { spw[rcur * 64 + lane] = packbf2(acc.x, acc.y); acc.x = acc.y = 0.f; rcur++; }
            acc.x = fmaf(w0, bf2f(d0 & 0xFFFF), acc.x);
            acc.y = fmaf(w0, bf2f(d0 >> 16),    acc.y);
        }
    }
    while (rcur < 8) { spw[rcur * 64 + lane] = packbf2(acc.x, acc.y); acc.x = acc.y = 0.f; rcur++; }
}

// ============================ MFMA GEMM: C[n,o] = s[n,:]@Bf + bias ============================
// A and B staged via async global_load_lds (16 B/lane), m97 2-barrier structure.

__global__ __launch_bounds__(256) void gemm_mfma(const short* __restrict__ s,
                                                 const short* __restrict__ Bf,
                                                 const float* __restrict__ bias,
                                                 float* __restrict__ Cout,
                                                 unsigned short* __restrict__ hbout,
                                                 int N, int relu) {
    __shared__ short As[4096];                    // [4 kb][128 rows][8] = 8 KB
    __shared__ short Bs[4096];                    // [4 kb][128 cols][8] = 8 KB
    int t = threadIdx.x;
    int w = t >> 6, lane = t & 63;
    int lhi = lane >> 4, llo = lane & 15;
    int n0 = blockIdx.x * 128;
    const char* sB = (const char*)s;
    const char* bB = (const char*)Bf;
    f32x4 acc[16] = {};

    for (int c = 0; c < 32; c++) {
        // ---- A: wave w stages kb=w for rows 0..127 (per-lane 16 B gather).
        //      4 waves jointly consume full 64 B lines of each s row.
        #pragma unroll
        for (int i = 0; i < 2; i++) {
            int row = i * 64 + lane;
            const void* gp = sB + (size_t)(n0 + row) * 2048 + c * 64 + w * 16;
            __builtin_amdgcn_global_load_lds(
                (gptr_t)gp, (lptr_t)((char*)As + w * 2048 + i * 1024), 16, 0, 0);
        }
        // ---- B: wave w stages bytes [w*2048, w*2048+2048) of the 8 KB chunk (coalesced).
        #pragma unroll
        for (int i = 0; i < 2; i++) {
            const void* gp = bB + (size_t)c * 8192 + w * 2048 + i * 1024 + lane * 16;
            __builtin_amdgcn_global_load_lds(
                (gptr_t)gp, (lptr_t)((char*)Bs + w * 2048 + i * 1024), 16, 0, 0);
        }
        __syncthreads();
        frag_t a0 = *(const frag_t*)(As + ((size_t)lhi * 128 + w * 32 + llo) * 8);
        frag_t a1 = *(const frag_t*)(As + ((size_t)lhi * 128 + w * 32 + llo + 16) * 8);
        #pragma unroll
        for (int ct = 0; ct < 8; ct++) {
            frag_t b = *(const frag_t*)(Bs + ((size_t)lhi * 128 + ct * 16 + llo) * 8);
            acc[ct]     = __builtin_amdgcn_mfma_f32_16x16x32_bf16(a0, b, acc[ct], 0, 0, 0);
            acc[8 + ct] = __builtin_amdgcn_mfma_f32_16x16x32_bf16(a1, b, acc[8 + ct], 0, 0, 0);
        }
        __syncthreads();
    }
    #pragma unroll
    for (int rt = 0; rt < 2; rt++) {
        #pragma unroll
        for (int ct = 0; ct < 8; ct++) {
            int col = ct * 16 + llo;
            float bv = bias[col];
            #pragma unroll
            for (int rg = 0; rg < 4; rg++) {
                int rown = n0 + w * 32 + rt * 16 + lhi * 4 + rg;
                if (rown < N) {
                    float v = acc[rt * 8 + ct][rg] + bv;
                    if (relu) v = fmaxf(v, 0.f);
                    if (Cout)  Cout[(size_t)rown * 128 + col] = v;
                    if (hbout) hbout[(size_t)rown * 128 + col] = (unsigned short)f2bf(v);
                }
            }
        }
    }
}

// ============================ launch ============================

extern "C" void kernel_launch(void* const* d_in, const int* in_sizes, int n_in,
                              void* d_out, int out_size, void* d_ws, size_t ws_size,
                              hipStream_t stream) {
    const float* z     = (const float*)d_in[0];
    const float* lin_w = (const float*)d_in[1];
    const float* lin_b = (const float*)d_in[2];
    const float* w1    = (const float*)d_in[3];
    const float* q1    = (const float*)d_in[4];
    const float* k1    = (const float*)d_in[5];
    const float* b1    = (const float*)d_in[6];
    const float* w2    = (const float*)d_in[7];
    const float* q2    = (const float*)d_in[8];
    const float* k2    = (const float*)d_in[9];
    const float* b2    = (const float*)d_in[10];
    const int*   ei    = (const int*)d_in[11];
    const int*   et    = (const int*)d_in[12];
    float* out = (float*)d_out;

    char* ws = (char*)d_ws;
    size_t off = 0;
    auto alloc = [&](size_t bytes) -> void* {
        void* p = ws + off;
        off += (bytes + 255) & ~(size_t)255;
        return p;
    };
    short* s     = (short*)alloc((size_t)N_NODES * 1024 * 2);   // 102.4 MB bf16 row-major
    unsigned short* hb = (unsigned short*)alloc((size_t)N_NODES * 128 * 2);  // 12.8 MB
    float* Q     = (float*)alloc((size_t)N_NODES * 8 * 4);
    float* K     = (float*)alloc((size_t)N_NODES * 8 * 4);
    int* sorted  = (int*)alloc((size_t)N_EDGES * 4);
    int* deg8    = (int*)alloc((size_t)NSEG * 4);
    int* rowp8   = (int*)alloc((size_t)(NSEG + 1) * 4);
    int* cursor8 = (int*)alloc((size_t)NSEG * 4);
    int* part    = (int*)alloc(1024 * 4);
    float* wq    = (float*)alloc(8 * 128 * 4);
    float* wk    = (float*)alloc(8 * 128 * 4);
    short* Bf    = (short*)alloc((size_t)1024 * 128 * 2);       // 256 KB bf16 blocked

    const int* src = ei;
    const int* dst = ei + N_EDGES;

    const int M = NSEG;
    const int nparts = (M + 1023) / 1024;   // 391

    // CSR build over (dst,et)
    hipMemsetAsync(deg8, 0, (size_t)M * 4, stream);
    hist_kernel<<<(N_EDGES + 255) / 256, 256, 0, stream>>>(dst, et, deg8, N_EDGES);
    scan_part<<<nparts, 256, 0, stream>>>(deg8, part, M);
    scan_mid<<<1, 512, 0, stream>>>(part, nparts, rowp8, M);
    scan_fix<<<nparts, 256, 0, stream>>>(deg8, part, rowp8, cursor8, M);
    fill_kernel<<<(N_EDGES + 255) / 256, 256, 0, stream>>>(src, dst, et, cursor8, sorted, N_EDGES);

    // h = z @ lin_w.T + lin_b  (bf16 out only)
    gemm_lin<<<(N_NODES + 63) / 64, 256, 0, stream>>>(z, lin_w, lin_b, hb, N_NODES);

    int mgrid = (N_NODES + 127) / 128;   // 391
    int agrid = (N_NODES + 3) / 4;       // 12500
    int qgrid = (N_NODES + 255) / 256;   // 196
    int wgrid = (131072 + 2048) / 256;   // 520

    // ---- layer 1: hb -> hb (relu)
    wprep_kernel<<<wgrid, 256, 0, stream>>>(w1, q1, k1, Bf, wq, wk);
    qk_table_kernel<<<qgrid, 256, 0, stream>>>(hb, wq, wk, Q, K, N_NODES);
    agg_s_kernel<<<agrid, 256, 0, stream>>>(hb, Q, K, rowp8, sorted, s, N_NODES);
    gemm_mfma<<<mgrid, 256, 0, stream>>>(s, Bf, b1, (float*)nullptr, hb, N_NODES, 1);

    // ---- layer 2: hb -> out (no relu)
    wprep_kernel<<<wgrid, 256, 0, stream>>>(w2, q2, k2, Bf, wq, wk);
    qk_table_kernel<<<qgrid, 256, 0, stream>>>(hb, wq, wk, Q, K, N_NODES);
    agg_s_kernel<<<agrid, 256, 0, stream>>>(hb, Q, K, rowp8, sorted, s, N_NODES);
    gemm_mfma<<<mgrid, 256, 0, stream>>>(s, Bf, b2, out, (unsigned short*)nullptr, N_NODES, 0);
}